// Round 9
// baseline (465.240 us; speedup 1.0000x reference)
//
#include <hip/hip_runtime.h>
#include <math.h>

#define NN 50000
#define EE 600000
#define MOUT 10000
#define DEGCAP 384
#define NT4 (NN * 4)

typedef short bf16x8 __attribute__((ext_vector_type(8)));
typedef float f32x4 __attribute__((ext_vector_type(4)));

__device__ __forceinline__ unsigned short f2bf(float x) {
    unsigned int u = __float_as_uint(x);
    u = (u + 0x7FFFu + ((u >> 16) & 1u)) >> 16;
    return (unsigned short)u;
}
__device__ __forceinline__ float bf2f(unsigned int b) {
    return __uint_as_float(b << 16);
}
__device__ __forceinline__ uint4 pack8bf(float4 a, float4 b) {
    uint4 r;
    r.x = (unsigned int)f2bf(a.x) | ((unsigned int)f2bf(a.y) << 16);
    r.y = (unsigned int)f2bf(a.z) | ((unsigned int)f2bf(a.w) << 16);
    r.z = (unsigned int)f2bf(b.x) | ((unsigned int)f2bf(b.y) << 16);
    r.w = (unsigned int)f2bf(b.z) | ((unsigned int)f2bf(b.w) << 16);
    return r;
}

// ============ merged weight prep + CSR/stats zeroing ============
// qkv weight rows 512..767 PERMUTED into 16B chunks (k[4t..4t+3], v[4t..4t+3]);
// qrel rows pre-scaled by p_rel/sqrt(32).
// msg weight stored COMPACT block-diagonal: msg_wt2[(l*4+r)*4096 + n*32 + d]
//   = m_rel[l][r][h=n>>5][d][e=n&31].
__global__ __launch_bounds__(256) void prep_kernel(
    const float* __restrict__ proj_w, const float* __restrict__ a_w,
    const float* __restrict__ q_w, const float* __restrict__ q_b,
    const float* __restrict__ a_rel,
    const float* __restrict__ k_w, const float* __restrict__ k_b,
    const float* __restrict__ v_w, const float* __restrict__ v_b,
    const float* __restrict__ m_rel, const float* __restrict__ p_rel,
    unsigned short* __restrict__ wt_pa, unsigned short* __restrict__ qkvw,
    float* __restrict__ fbias, unsigned short* __restrict__ msg_wt,
    int* __restrict__ cnt, float* __restrict__ stats)
{
    const int b = blockIdx.x, t = threadIdx.x;
    if (b < 192) {                       // proj^T, a_w0^T, a_w1^T
        int wi = b >> 6;
        int flat = (b & 63) * 256 + t;
        int n = flat >> 7, c = flat & 127;
        const float* src = (wi == 0) ? proj_w : (wi == 1) ? a_w : a_w + 16384;
        wt_pa[(size_t)wi * 16384 + n * 128 + c] = f2bf(src[c * 128 + n]);
    } else if (b < 960) {                // fused qkv weight [768][128] per layer
        int q = b - 192;
        int l = q >= 384 ? 1 : 0;
        int flat = (q - l * 384) * 256 + t;
        int nrow = flat >> 7, c = flat & 127;
        unsigned short* wt = qkvw + (size_t)l * 98304;
        float* fb = fbias + l * 768;
        if (nrow < 512) {
            int r = nrow >> 7, hh = (nrow >> 5) & 3, d = nrow & 31;
            float prl = p_rel[l * 16 + r * 4 + hh] * 0.17677669529663687f;
            const float* qwc = q_w + (size_t)l * 16384 + c * 128 + hh * 32;
            const float* ar  = a_rel + (size_t)(l * 4 + r) * 4096 + hh * 1024 + d * 32;
            float s = 0.f;
            #pragma unroll 8
            for (int e = 0; e < 32; ++e) s += qwc[e] * ar[e];
            wt[(size_t)nrow * 128 + c] = f2bf(s * prl);
            if (c == 0) {
                const float* qb = q_b + l * 128 + hh * 32;
                float bb = 0.f;
                #pragma unroll 8
                for (int e = 0; e < 32; ++e) bb += qb[e] * ar[e];
                fb[nrow] = bb * prl;
            }
        } else {                         // k/v 16B-chunk rows: t-th chunk = k[4t..4t+3], v[4t..4t+3]
            int j = nrow - 512;
            int tt = j >> 3, s = j & 7;
            int col = 4 * tt + (s & 3);
            const float* w  = (s < 4) ? k_w : v_w;
            const float* bb = (s < 4) ? k_b : v_b;
            wt[(size_t)nrow * 128 + c] = f2bf(w[(size_t)l * 16384 + c * 128 + col]);
            if (c == 0) fb[nrow] = bb[l * 128 + col];
        }
    } else if (b < 1088) {               // compact msg weight: 2 layers x 4 rel x [128 n][32 d]
        int q = b - 960;
        int l = q >= 64 ? 1 : 0;
        int flat = (q - l * 64) * 256 + t;     // 0 .. 16383
        int r = flat >> 12, rem = flat & 4095;
        int n = rem >> 5, d = rem & 31;
        float val = m_rel[(size_t)(l * 4 + r) * 4096 + (n >> 5) * 1024 + d * 32 + (n & 31)];
        msg_wt[(size_t)l * 16384 + r * 4096 + n * 32 + d] = f2bf(val);
    } else {                             // zero cnt + stats
        int i = (b - 1088) * 256 + t;
        if (i < NT4) cnt[i] = 0;
        if (i < 256) stats[i] = 0.f;
    }
}

// ============ CSR build ============
__global__ __launch_bounds__(256) void hist_kernel(const int* __restrict__ ei,
    const int* __restrict__ et, int* __restrict__ cnt, int E)
{
    int e = blockIdx.x * 256 + threadIdx.x;
    if (e < E) atomicAdd(&cnt[ei[E + e] * 4 + et[e]], 1);
}

__global__ __launch_bounds__(256) void scan_block_kernel(const int* __restrict__ cnt,
    int* __restrict__ excl, int* __restrict__ bsum, int n)
{
    __shared__ int tmp[256];
    int i = blockIdx.x * 256 + threadIdx.x;
    int v = (i < n) ? cnt[i] : 0;
    tmp[threadIdx.x] = v;
    __syncthreads();
    for (int ofs = 1; ofs < 256; ofs <<= 1) {
        int t = (threadIdx.x >= ofs) ? tmp[threadIdx.x - ofs] : 0;
        __syncthreads();
        tmp[threadIdx.x] += t;
        __syncthreads();
    }
    if (i < n) excl[i] = tmp[threadIdx.x] - v;
    if (threadIdx.x == 255) bsum[blockIdx.x] = tmp[255];
}

// per-block prefix over bsum; ALSO zeroes the idx-mask region (reuses dead cnt[0:12500))
__global__ __launch_bounds__(256) void scan_add_kernel(int* __restrict__ excl,
    const int* __restrict__ bsum, int* __restrict__ fill,
    int* __restrict__ maskz, int n, int total)
{
    __shared__ int red[256];
    const int b = blockIdx.x;
    int partial = 0;
    for (int j = threadIdx.x; j < b; j += 256) partial += bsum[j];
    red[threadIdx.x] = partial;
    __syncthreads();
    for (int ofs = 128; ofs > 0; ofs >>= 1) {
        if (threadIdx.x < ofs) red[threadIdx.x] += red[threadIdx.x + ofs];
        __syncthreads();
    }
    int prefix = red[0];
    int i = b * 256 + threadIdx.x;
    if (i < n) {
        int o = excl[i] + prefix;
        excl[i] = o;
        fill[i] = o;
    }
    if (i < 12500) maskz[i] = 0;         // cnt region is dead after scan_block
    if (b == 0 && threadIdx.x == 0) excl[n] = total;
}

// scatter + idx-membership mask set (mask lives in old cnt region)
__global__ __launch_bounds__(256) void scatter_kernel(const int* __restrict__ ei,
    const int* __restrict__ et, int* __restrict__ fill, int* __restrict__ pack,
    const int* __restrict__ idxp, unsigned char* __restrict__ mask, int Mo, int E)
{
    int e = blockIdx.x * 256 + threadIdx.x;
    if (e >= E) return;
    int seg = ei[E + e] * 4 + et[e];
    int p = atomicAdd(&fill[seg], 1);
    pack[p] = ei[e];
    if (e < Mo) mask[idxp[e]] = 1;
}

// ============ proj GEMM + BN-stats epilogue, A loaded as f32 and cast in-register ============
__global__ __launch_bounds__(256) void projstats_kernel(
    const float* __restrict__ X, const unsigned short* __restrict__ Wt,
    const float* __restrict__ bias, unsigned short* __restrict__ Cb,
    float* __restrict__ stats, int M)
{
    __shared__ unsigned short As[128 * 40];
    __shared__ unsigned short Bs[128 * 40];
    const int t = threadIdx.x;
    const int wave = t >> 6, lane = t & 63;
    const int quad = lane >> 4, l16 = lane & 15;
    const int row0 = blockIdx.x * 128;
    const int wr = (wave & 1) * 64, wc = (wave >> 1) * 64;
    const int sr = t >> 1, sc = (t & 1) * 16;
    const int grow = row0 + sr;

    f32x4 acc[4][4];
    #pragma unroll
    for (int i = 0; i < 4; ++i)
        #pragma unroll
        for (int j = 0; j < 4; ++j)
            acc[i][j] = (f32x4){0.f, 0.f, 0.f, 0.f};

    uint4 av0 = make_uint4(0,0,0,0), av1 = av0, bv0, bv1;
    if (grow < M) {
        const float4* ap = (const float4*)(X + (size_t)grow * 128 + sc);
        av0 = pack8bf(ap[0], ap[1]);
        av1 = pack8bf(ap[2], ap[3]);
    }
    {
        const uint4* bp = (const uint4*)(Wt + (size_t)sr * 128 + sc);
        bv0 = bp[0]; bv1 = bp[1];
    }
    for (int it = 0; it < 4; ++it) {
        __syncthreads();
        *(uint4*)(As + sr * 40 + sc)     = av0;
        *(uint4*)(As + sr * 40 + sc + 8) = av1;
        *(uint4*)(Bs + sr * 40 + sc)     = bv0;
        *(uint4*)(Bs + sr * 40 + sc + 8) = bv1;
        __syncthreads();
        if (it + 1 < 4) {
            int kb = (it + 1) * 32;
            if (grow < M) {
                const float4* ap = (const float4*)(X + (size_t)grow * 128 + kb + sc);
                av0 = pack8bf(ap[0], ap[1]);
                av1 = pack8bf(ap[2], ap[3]);
            }
            const uint4* bp = (const uint4*)(Wt + (size_t)sr * 128 + kb + sc);
            bv0 = bp[0]; bv1 = bp[1];
        }
        bf16x8 af[4], bfr[4];
        #pragma unroll
        for (int f = 0; f < 4; ++f) {
            af[f]  = *(const bf16x8*)(As + (wr + f * 16 + l16) * 40 + quad * 8);
            bfr[f] = *(const bf16x8*)(Bs + (wc + f * 16 + l16) * 40 + quad * 8);
        }
        #pragma unroll
        for (int fr = 0; fr < 4; ++fr)
            #pragma unroll
            for (int fc = 0; fc < 4; ++fc)
                acc[fr][fc] = __builtin_amdgcn_mfma_f32_16x16x32_bf16(
                    af[fr], bfr[fc], acc[fr][fc], 0, 0, 0);
    }

    #pragma unroll
    for (int fc = 0; fc < 4; ++fc) {
        const int col = wc + fc * 16 + l16;
        const float bv = bias[col];
        float s = 0.f, s2 = 0.f;
        #pragma unroll
        for (int fr = 0; fr < 4; ++fr)
            #pragma unroll
            for (int reg = 0; reg < 4; ++reg) {
                int row = row0 + wr + fr * 16 + quad * 4 + reg;
                float val = acc[fr][fc][reg] + bv;
                if (row < M) {
                    Cb[(size_t)row * 128 + col] = f2bf(val);
                    s += val; s2 += val * val;
                }
            }
        s  += __shfl_xor(s, 16);  s  += __shfl_xor(s, 32);
        s2 += __shfl_xor(s2, 16); s2 += __shfl_xor(s2, 32);
        if (quad == 0) {
            atomicAdd(&stats[col], s);
            atomicAdd(&stats[128 + col], s2);
        }
    }
}

// ============ BN-apply + qkv0 GEMM: hn = BN(h); qkv = hn @ qkvw^T + fbias ============
// 64-K-col B staging (stride-68), 2 MFMA sub-its per barrier pair: 24 barriers total.
__global__ __launch_bounds__(256) void bnqkv_kernel(
    const unsigned short* __restrict__ hb, const float* __restrict__ stats,
    const float* __restrict__ gamma, const float* __restrict__ beta,
    const unsigned short* __restrict__ qkvw, const float* __restrict__ fbias,
    unsigned short* __restrict__ hn, unsigned short* __restrict__ qkv, int M)
{
    __shared__ unsigned short hS[128 * 136];
    __shared__ unsigned short Bs[128 * 68];
    __shared__ float mulS[128], addS[128];
    const int t = threadIdx.x;
    const int row0 = blockIdx.x * 128;
    if (t < 128) {
        float invN = 1.f / 50000.f;
        float mu = stats[t] * invN;
        float var = stats[128 + t] * invN - mu * mu;
        float ml = rsqrtf(var + 1e-5f) * gamma[t];
        mulS[t] = ml;
        addS[t] = beta[t] - mu * ml;
    }
    __syncthreads();
    #pragma unroll
    for (int u = 0; u < 8; ++u) {
        int li = t + u * 256;                 // uint4 index; 16 per row
        int row = li >> 4, c0 = (li & 15) * 8;
        uint4 pk = make_uint4(0, 0, 0, 0);
        if (row0 + row < M)
            pk = ((const uint4*)(hb + (size_t)(row0 + row) * 128))[li & 15];
        unsigned int w[4] = {pk.x, pk.y, pk.z, pk.w};
        uint4 o;
        unsigned int ov[4];
        #pragma unroll
        for (int g = 0; g < 4; ++g) {
            int c = c0 + g * 2;
            float a0 = bf2f(w[g] & 0xFFFFu) * mulS[c]     + addS[c];
            float a1 = bf2f(w[g] >> 16)     * mulS[c + 1] + addS[c + 1];
            ov[g] = (unsigned int)f2bf(a0) | ((unsigned int)f2bf(a1) << 16);
        }
        o.x = ov[0]; o.y = ov[1]; o.z = ov[2]; o.w = ov[3];
        *(uint4*)(hS + row * 136 + c0) = o;
        if (row0 + row < M)
            ((uint4*)(hn + (size_t)(row0 + row) * 128))[li & 15] = o;
    }
    __syncthreads();

    const int wave = t >> 6, lane = t & 63;
    const int quad = lane >> 4, l16 = lane & 15;
    const int wr = (wave & 1) * 64, wcl = (wave >> 1) * 64;
    const int sr = t >> 1;
    const int half = (t & 1) * 32;       // 32-short half of a 64-col stage

    uint4 pv[4];
    {
        const uint4* bp = (const uint4*)(qkvw + (size_t)sr * 128 + half);
        #pragma unroll
        for (int j = 0; j < 4; ++j) pv[j] = bp[j];
    }
    for (int ch = 0; ch < 6; ++ch) {
        f32x4 acc[4][4];
        #pragma unroll
        for (int i = 0; i < 4; ++i)
            #pragma unroll
            for (int j = 0; j < 4; ++j)
                acc[i][j] = (f32x4){0.f, 0.f, 0.f, 0.f};
        for (int sup = 0; sup < 2; ++sup) {
            __syncthreads();
            #pragma unroll
            for (int j = 0; j < 4; ++j)
                *(uint4*)(Bs + sr * 68 + half + j * 8) = pv[j];
            __syncthreads();
            int ns = sup + 1, nc = ch;
            if (ns == 2) { ns = 0; ++nc; }
            if (nc < 6) {
                const uint4* bp = (const uint4*)(qkvw + (size_t)(nc * 128 + sr) * 128 + ns * 64 + half);
                #pragma unroll
                for (int j = 0; j < 4; ++j) pv[j] = bp[j];
            }
            #pragma unroll
            for (int it2 = 0; it2 < 2; ++it2) {
                const int it = sup * 2 + it2;
                bf16x8 af[4], bfr[4];
                #pragma unroll
                for (int f = 0; f < 4; ++f) {
                    af[f]  = *(const bf16x8*)(hS + (wr + f * 16 + l16) * 136 + it * 32 + quad * 8);
                    bfr[f] = *(const bf16x8*)(Bs + (wcl + f * 16 + l16) * 68 + it2 * 32 + quad * 8);
                }
                #pragma unroll
                for (int fr = 0; fr < 4; ++fr)
                    #pragma unroll
                    for (int fc = 0; fc < 4; ++fc)
                        acc[fr][fc] = __builtin_amdgcn_mfma_f32_16x16x32_bf16(
                            af[fr], bfr[fc], acc[fr][fc], 0, 0, 0);
            }
        }
        float b4[4];
        #pragma unroll
        for (int fc = 0; fc < 4; ++fc)
            b4[fc] = fbias[ch * 128 + wcl + fc * 16 + l16];
        #pragma unroll
        for (int fr = 0; fr < 4; ++fr)
            #pragma unroll
            for (int reg = 0; reg < 4; ++reg) {
                int row = row0 + wr + fr * 16 + quad * 4 + reg;
                if (row >= M) continue;
                #pragma unroll
                for (int fc = 0; fc < 4; ++fc) {
                    int col = ch * 128 + wcl + fc * 16 + l16;
                    qkv[(size_t)row * 768 + col] = f2bf(acc[fr][fc][reg] + b4[fc]);
                }
            }
    }
}

// ============ fused attention: per-node wave, PAIR processing (2 edges across wave halves) ====
__global__ __launch_bounds__(256) void agg_fused_kernel(
    const unsigned short* __restrict__ qkv,
    const unsigned short* __restrict__ qbuf, int qpitch,
    const int* __restrict__ off4, const int* __restrict__ pack,
    const int* __restrict__ rowmap, unsigned short* __restrict__ aggb, int count)
{
    __shared__ int spack[4][DEGCAP];
    const int wv = threadIdx.x >> 6;
    const int lane = threadIdx.x & 63;
    const int l32 = lane & 31;
    const int hi = lane >> 5;
    const int unit = blockIdx.x * 4 + wv;
    if (unit >= count) return;                 // no __syncthreads in this kernel
    const int node = rowmap ? __builtin_amdgcn_readfirstlane(rowmap[unit]) : unit;

    // q dims [4*l32 .. 4*l32+3] per run (both halves need the same dims)
    const uint2* qrow = (const uint2*)(qbuf + (size_t)unit * qpitch);
    uint2 quv[4];
    #pragma unroll
    for (int r = 0; r < 4; ++r) quv[r] = qrow[r * 32 + l32];

    int off_r[5];
    #pragma unroll
    for (int i = 0; i < 5; ++i)
        off_r[i] = __builtin_amdgcn_readfirstlane(off4[node * 4 + i]);
    const int beg = off_r[0];
    const int deg = off_r[4] - beg;
    const bool cached = deg <= DEGCAP;

    if (cached) {
        for (int i = lane; i < deg; i += 64) spack[wv][i] = pack[beg + i];
        asm volatile("s_waitcnt vmcnt(0) lgkmcnt(0)" ::: "memory");
    }

    uint2 outw[4];
    #pragma unroll
    for (int r = 0; r < 4; ++r) {
        float q0 = bf2f(quv[r].x & 0xFFFFu), q1 = bf2f(quv[r].x >> 16);
        float q2 = bf2f(quv[r].y & 0xFFFFu), q3 = bf2f(quv[r].y >> 16);
        float den = 0.f, a0 = 0.f, a1 = 0.f, a2 = 0.f, a3 = 0.f;

        if (cached) {
            const int rb = off_r[r] - beg, re = off_r[r + 1] - beg;
            for (int i = rb; i < re; i += 4) {
                int i0 = i + hi;      if (i0 >= re) i0 = re - 1;
                int i1 = i + 2 + hi;  if (i1 >= re) i1 = re - 1;
                int s0 = spack[wv][i0], s1 = spack[wv][i1];
                uint4 kv0 = *(const uint4*)(qkv + (size_t)s0 * 768 + 512 + l32 * 8);
                uint4 kv1 = *(const uint4*)(qkv + (size_t)s1 * 768 + 512 + l32 * 8);
                {
                    float p = q0 * bf2f(kv0.x & 0xFFFFu) + q1 * bf2f(kv0.x >> 16)
                            + q2 * bf2f(kv0.y & 0xFFFFu) + q3 * bf2f(kv0.y >> 16);
                    p += __shfl_xor(p, 1); p += __shfl_xor(p, 2); p += __shfl_xor(p, 4);
                    float e = __expf(fminf(fmaxf(p, -80.f), 80.f));
                    if (i + hi >= re) e = 0.f;
                    den += e;
                    a0 += e * bf2f(kv0.z & 0xFFFFu); a1 += e * bf2f(kv0.z >> 16);
                    a2 += e * bf2f(kv0.w & 0xFFFFu); a3 += e * bf2f(kv0.w >> 16);
                }
                {
                    float p = q0 * bf2f(kv1.x & 0xFFFFu) + q1 * bf2f(kv1.x >> 16)
                            + q2 * bf2f(kv1.y & 0xFFFFu) + q3 * bf2f(kv1.y >> 16);
                    p += __shfl_xor(p, 1); p += __shfl_xor(p, 2); p += __shfl_xor(p, 4);
                    float e = __expf(fminf(fmaxf(p, -80.f), 80.f));
                    if (i + 2 + hi >= re) e = 0.f;
                    den += e;
                    a0 += e * bf2f(kv1.z & 0xFFFFu); a1 += e * bf2f(kv1.z >> 16);
                    a2 += e * bf2f(kv1.w & 0xFFFFu); a3 += e * bf2f(kv1.w >> 16);
                }
            }
        } else {   // giant-degree fallback: pair walk straight from pack
            const int pe_end = off_r[r + 1];
            for (int pp = off_r[r]; pp < pe_end; pp += 2) {
                int pe = pp + hi; if (pe >= pe_end) pe = pe_end - 1;
                int src = pack[pe];
                uint4 kv = *(const uint4*)(qkv + (size_t)src * 768 + 512 + l32 * 8);
                float p = q0 * bf2f(kv.x & 0xFFFFu) + q1 * bf2f(kv.x >> 16)
                        + q2 * bf2f(kv.y & 0xFFFFu) + q3 * bf2f(kv.y >> 16);
                p += __shfl_xor(p, 1); p += __shfl_xor(p, 2); p += __shfl_xor(p, 4);
                float e = __expf(fminf(fmaxf(p, -80.f), 80.f));
                if (pp + hi >= pe_end) e = 0.f;
                den += e;
                a0 += e * bf2f(kv.z & 0xFFFFu); a1 += e * bf2f(kv.z >> 16);
                a2 += e * bf2f(kv.w & 0xFFFFu); a3 += e * bf2f(kv.w >> 16);
            }
        }
        // merge the two halves (lane l and l+32 hold the same dims, different edges)
        den += __shfl_xor(den, 32);
        a0  += __shfl_xor(a0, 32);
        a1  += __shfl_xor(a1, 32);
        a2  += __shfl_xor(a2, 32);
        a3  += __shfl_xor(a3, 32);
        float inv = den > 0.f ? 1.f / den : 0.f;
        outw[r].x = (unsigned int)f2bf(a0 * inv) | ((unsigned int)f2bf(a1 * inv) << 16);
        outw[r].y = (unsigned int)f2bf(a2 * inv) | ((unsigned int)f2bf(a3 * inv) << 16);
    }
    if (hi == 0) {
        uint2* op = (uint2*)(aggb + (size_t)unit * 512);
        #pragma unroll
        for (int r = 0; r < 4; ++r) op[r * 32 + l32] = outw[r];
    }
}

// ============ layer-0 MLP + qkv1-kv (block-diag stage 1; 64-col B staging stages 2/3) ============
__global__ __launch_bounds__(256) void mlpqkv_kernel(
    const unsigned short* __restrict__ A, const unsigned short* __restrict__ W3c,
    const unsigned short* __restrict__ AWt, const float* __restrict__ a_bias,
    const float* __restrict__ skipv, const unsigned short* __restrict__ hres,
    const unsigned short* __restrict__ qkvw1, const float* __restrict__ fbias1,
    const unsigned char* __restrict__ mask,
    unsigned short* __restrict__ h1, unsigned short* __restrict__ qkv, int M)
{
    __shared__ unsigned short Bs[128 * 68];
    __shared__ unsigned short msgS[128 * 136];
    const int t = threadIdx.x;
    const int wave = t >> 6, lane = t & 63;
    const int quad = lane >> 4, l16 = lane & 15;
    const int row0 = blockIdx.x * 128;
    const int wr = (wave & 1) * 64, wcl = (wave >> 1) * 64;
    const int sr = t >> 1, scc = (t & 1) * 16;
    const int half = (t & 1) * 32;
    const int scc2 = (t & 1) * 64;
    const int grow = row0 + sr;
    const bool rvalid = grow < M;
    const int h2b = wcl >> 5;            // first head of this wave's output cols (0 or 2)

    // ---- stage 1: block-diagonal, 4 its (it == relation r), K=32 per output head ----
    f32x4 acc[4][4];
    #pragma unroll
    for (int i = 0; i < 4; ++i)
        #pragma unroll
        for (int j = 0; j < 4; ++j)
            acc[i][j] = (f32x4){0.f, 0.f, 0.f, 0.f};

    uint4 av[8];
    #pragma unroll
    for (int j = 0; j < 8; ++j) av[j] = make_uint4(0, 0, 0, 0);
    if (rvalid) {
        const uint4* ap = (const uint4*)(A + (size_t)grow * 512 + scc2);
        #pragma unroll
        for (int j = 0; j < 8; ++j) av[j] = ap[j];
    }
    uint4 bw0, bw1;
    {
        const uint4* bp = (const uint4*)(W3c + sr * 32 + scc);
        bw0 = bp[0]; bw1 = bp[1];
    }
    for (int it = 0; it < 4; ++it) {
        __syncthreads();
        #pragma unroll
        for (int j = 0; j < 8; ++j)
            *(uint4*)(msgS + sr * 136 + scc2 + j * 8) = av[j];
        *(uint4*)(Bs + sr * 68 + scc)     = bw0;
        *(uint4*)(Bs + sr * 68 + scc + 8) = bw1;
        __syncthreads();
        if (it + 1 < 4) {
            if (rvalid) {
                const uint4* ap = (const uint4*)(A + (size_t)grow * 512 + (it + 1) * 128 + scc2);
                #pragma unroll
                for (int j = 0; j < 8; ++j) av[j] = ap[j];
            }
            const uint4* bp = (const uint4*)(W3c + (it + 1) * 4096 + sr * 32 + scc);
            bw0 = bp[0]; bw1 = bp[1];
        }
        bf16x8 af2[2][4], bfr[4];
        #pragma unroll
        for (int g = 0; g < 2; ++g)
            #pragma unroll
            for (int f = 0; f < 4; ++f)
                af2[g][f] = *(const bf16x8*)(msgS + (wr + f * 16 + l16) * 136 + (h2b + g) * 32 + quad * 8);
        #pragma unroll
        for (int f = 0; f < 4; ++f)
            bfr[f] = *(const bf16x8*)(Bs + (wcl + f * 16 + l16) * 68 + quad * 8);
        #pragma unroll
        for (int fr = 0; fr < 4; ++fr)
            #pragma unroll
            for (int fc = 0; fc < 4; ++fc)
                acc[fr][fc] = __builtin_amdgcn_mfma_f32_16x16x32_bf16(
                    af2[fc >> 1][fr], bfr[fc], acc[fr][fc], 0, 0, 0);
    }
    __syncthreads();      // all stage-1 msgS reads complete before gelu overwrite

    // gelu -> msgS
    #pragma unroll
    for (int fr = 0; fr < 4; ++fr)
        #pragma unroll
        for (int reg = 0; reg < 4; ++reg) {
            int rl = wr + fr * 16 + quad * 4 + reg;
            #pragma unroll
            for (int fc = 0; fc < 4; ++fc) {
                int col = wcl + fc * 16 + l16;
                float v = acc[fr][fc][reg];
                float gl = 0.5f * v * (1.f + erff(v * 0.70710678118654752f));
                msgS[rl * 136 + col] = f2bf(gl);
            }
        }

    // stage 2: K = 128 from msgS vs AWt (64-col staging, 2 sub-its per barrier pair)
    f32x4 acc2[4][4];
    #pragma unroll
    for (int i = 0; i < 4; ++i)
        #pragma unroll
        for (int j = 0; j < 4; ++j)
            acc2[i][j] = (f32x4){0.f, 0.f, 0.f, 0.f};
    uint4 pv[4];
    {
        const uint4* bp = (const uint4*)(AWt + (size_t)sr * 128 + half);
        #pragma unroll
        for (int j = 0; j < 4; ++j) pv[j] = bp[j];
    }
    for (int sup = 0; sup < 2; ++sup) {
        __syncthreads();
        #pragma unroll
        for (int j = 0; j < 4; ++j)
            *(uint4*)(Bs + sr * 68 + half + j * 8) = pv[j];
        __syncthreads();
        if (sup == 0) {
            const uint4* bp = (const uint4*)(AWt + (size_t)sr * 128 + 64 + half);
            #pragma unroll
            for (int j = 0; j < 4; ++j) pv[j] = bp[j];
        } else {   // prefetch stage-3 (ch=4, sup=0)
            const uint4* bp = (const uint4*)(qkvw1 + (size_t)(4 * 128 + sr) * 128 + half);
            #pragma unroll
            for (int j = 0; j < 4; ++j) pv[j] = bp[j];
        }
        #pragma unroll
        for (int it2 = 0; it2 < 2; ++it2) {
            const int it = sup * 2 + it2;
            bf16x8 af[4], bfr[4];
            #pragma unroll
            for (int f = 0; f < 4; ++f) {
                af[f]  = *(const bf16x8*)(msgS + (wr + f * 16 + l16) * 136 + it * 32 + quad * 8);
                bfr[f] = *(const bf16x8*)(Bs + (wcl + f * 16 + l16) * 68 + it2 * 32 + quad * 8);
            }
            #pragma unroll
            for (int fr = 0; fr < 4; ++fr)
                #pragma unroll
                for (int fc = 0; fc < 4; ++fc)
                    acc2[fr][fc] = __builtin_amdgcn_mfma_f32_16x16x32_bf16(
                        af[fr], bfr[fc], acc2[fr][fc], 0, 0, 0);
        }
    }

    const float gate = 1.f / (1.f + __expf(-skipv[0]));
    __syncthreads();                            // all stage-2 msgS reads complete
    #pragma unroll
    for (int fr = 0; fr < 4; ++fr)
        #pragma unroll
        for (int reg = 0; reg < 4; ++reg) {
            int rl = wr + fr * 16 + quad * 4 + reg;
            int row = row0 + rl;
            const bool rv = row < M;
            const bool mw = rv && mask[row];    // h1 only ever read at idx rows
            #pragma unroll
            for (int fc = 0; fc < 4; ++fc) {
                int col = wcl + fc * 16 + l16;
                float val = acc2[fr][fc][reg] + a_bias[col];
                float nv = val;
                if (rv) {
                    unsigned int hu = hres[(size_t)row * 128 + col];
                    nv = gate * val + (1.f - gate) * bf2f(hu);
                    if (mw) h1[(size_t)row * 128 + col] = f2bf(nv);
                }
                msgS[rl * 136 + col] = f2bf(nv);   // h1 tile for stage 3
            }
        }

    // stage 3: qkv1 KV ONLY = h1 @ qkvw1^T cols 512..767 (64-col staging)
    for (int ch = 4; ch < 6; ++ch) {
        f32x4 acc3[4][4];
        #pragma unroll
        for (int i = 0; i < 4; ++i)
            #pragma unroll
            for (int j = 0; j < 4; ++j)
                acc3[i][j] = (f32x4){0.f, 0.f, 0.f, 0.f};
        for (int sup = 0; sup < 2; ++sup) {
            __syncthreads();
            #pragma unroll
            for (int j = 0; j < 4; ++j)
                *(uint4*)(Bs + sr * 68 + half + j * 8) = pv[j];
            __syncthreads();
            int ns = sup + 1, nc = ch;
            if (ns == 2) { ns = 0; ++nc; }
            if (nc < 6) {
                const uint4* bp = (const uint4*)(qkvw1 + (size_t)(nc * 128 + sr) * 128 + ns * 64 + half);
                #pragma unroll
                for (int j = 0; j < 4; ++j) pv[j] = bp[j];
            }
            #pragma unroll
            for (int it2 = 0; it2 < 2; ++it2) {
                const int it = sup * 2 + it2;
                bf16x8 af[4], bfr[4];
                #pragma unroll
                for (int f = 0; f < 4; ++f) {
                    af[f]  = *(const bf16x8*)(msgS + (wr + f * 16 + l16) * 136 + it * 32 + quad * 8);
                    bfr[f] = *(const bf16x8*)(Bs + (wcl + f * 16 + l16) * 68 + it2 * 32 + quad * 8);
                }
                #pragma unroll
                for (int fr = 0; fr < 4; ++fr)
                    #pragma unroll
                    for (int fc = 0; fc < 4; ++fc)
                        acc3[fr][fc] = __builtin_amdgcn_mfma_f32_16x16x32_bf16(
                            af[fr], bfr[fc], acc3[fr][fc], 0, 0, 0);
            }
        }
        float b4[4];
        #pragma unroll
        for (int fc = 0; fc < 4; ++fc)
            b4[fc] = fbias1[ch * 128 + wcl + fc * 16 + l16];
        #pragma unroll
        for (int fr = 0; fr < 4; ++fr)
            #pragma unroll
            for (int reg = 0; reg < 4; ++reg) {
                int row = row0 + wr + fr * 16 + quad * 4 + reg;
                if (row >= M) continue;
                #pragma unroll
                for (int fc = 0; fc < 4; ++fc) {
                    int col = ch * 128 + wcl + fc * 16 + l16;
                    qkv[(size_t)row * 768 + col] = f2bf(acc3[fr][fc][reg] + b4[fc]);
                }
            }
    }
}

// ============ compact layer-1 q: q1[u] = h1[idx[u]] @ qkvw1_q^T + fbias1_q  ([MOUT][512]) ====
__global__ __launch_bounds__(256) void q1_kernel(
    const unsigned short* __restrict__ h1, const int* __restrict__ idxp,
    const unsigned short* __restrict__ qkvw1, const float* __restrict__ fbias1,
    unsigned short* __restrict__ q1, int M)
{
    __shared__ unsigned short hS[128 * 136];
    __shared__ unsigned short Bs[128 * 68];
    const int t = threadIdx.x;
    const int row0 = blockIdx.x * 128;
    #pragma unroll
    for (int u = 0; u < 8; ++u) {
        int li = t + u * 256;                 // uint4 index; 16 per row
        int row = li >> 4, c = li & 15;
        uint4 pk = make_uint4(0, 0, 0, 0);
        if (row0 + row < M) {
            int node = idxp[row0 + row];
            pk = ((const uint4*)(h1 + (size_t)node * 128))[c];
        }
        *(uint4*)(hS + row * 136 + c * 8) = pk;
    }
    __syncthreads();

    const int wave = t >> 6, lane = t & 63;
    const int quad = lane >> 4, l16 = lane & 15;
    const int wr = (wave & 1) * 64, wcl = (wave >> 1) * 64;
    const int sr = t >> 1;
    const int half = (t & 1) * 32;
    uint4 pv[4];
    {
        const uint4* bp = (const uint4*)(qkvw1 + (size_t)sr * 128 + half);
        #pragma unroll
        for (int j = 0; j < 4; ++j) pv[j] = bp[j];
    }
    for (int ch = 0; ch < 4; ++ch) {
        f32x4 acc[4][4];
        #pragma unroll
        for (int i = 0; i < 4; ++i)
            #pragma unroll
            for (int j = 0; j < 4; ++j)
                acc[i][j] = (f32x4){0.f, 0.f, 0.f, 0.f};
        for (int sup = 0; sup < 2; ++sup) {
            __syncthreads();
            #pragma unroll
            for (int j = 0; j < 4; ++j)
                *(uint4*)(Bs + sr * 68 + half + j * 8) = pv[j];
            __syncthreads();
            int ns = sup + 1, nc = ch;
            if (ns == 2) { ns = 0; ++nc; }
            if (nc < 4) {
                const uint4* bp = (const uint4*)(qkvw1 + (size_t)(nc * 128 + sr) * 128 + ns * 64 + half);
                #pragma unroll
                for (int j = 0; j < 4; ++j) pv[j] = bp[j];
            }
            #pragma unroll
            for (int it2 = 0; it2 < 2; ++it2) {
                const int it = sup * 2 + it2;
                bf16x8 af[4], bfr[4];
                #pragma unroll
                for (int f = 0; f < 4; ++f) {
                    af[f]  = *(const bf16x8*)(hS + (wr + f * 16 + l16) * 136 + it * 32 + quad * 8);
                    bfr[f] = *(const bf16x8*)(Bs + (wcl + f * 16 + l16) * 68 + it2 * 32 + quad * 8);
                }
                #pragma unroll
                for (int fr = 0; fr < 4; ++fr)
                    #pragma unroll
                    for (int fc = 0; fc < 4; ++fc)
                        acc[fr][fc] = __builtin_amdgcn_mfma_f32_16x16x32_bf16(
                            af[fr], bfr[fc], acc[fr][fc], 0, 0, 0);
            }
        }
        float b4[4];
        #pragma unroll
        for (int fc = 0; fc < 4; ++fc)
            b4[fc] = fbias1[ch * 128 + wcl + fc * 16 + l16];
        #pragma unroll
        for (int fr = 0; fr < 4; ++fr)
            #pragma unroll
            for (int reg = 0; reg < 4; ++reg) {
                int row = row0 + wr + fr * 16 + quad * 4 + reg;
                if (row >= M) continue;
                #pragma unroll
                for (int fc = 0; fc < 4; ++fc) {
                    int col = ch * 128 + wcl + fc * 16 + l16;
                    q1[(size_t)row * 512 + col] = f2bf(acc[fr][fc][reg] + b4[fc]);
                }
            }
    }
}

// ============ layer-1 MLP (compact rows, block-diag stage 1; 64-col stage 2) ============
__global__ __launch_bounds__(256) void mlp1_kernel(
    const unsigned short* __restrict__ A, const unsigned short* __restrict__ W3c,
    const unsigned short* __restrict__ AWt, const float* __restrict__ a_bias,
    const float* __restrict__ skipv, const unsigned short* __restrict__ hres,
    const int* __restrict__ rowmap, float* __restrict__ out, int M)
{
    __shared__ unsigned short Bs[128 * 68];
    __shared__ unsigned short msgS[128 * 136];
    const int t = threadIdx.x;
    const int wave = t >> 6, lane = t & 63;
    const int quad = lane >> 4, l16 = lane & 15;
    const int row0 = blockIdx.x * 128;
    const int wr = (wave & 1) * 64, wcl = (wave >> 1) * 64;
    const int sr = t >> 1, scc = (t & 1) * 16;
    const int half = (t & 1) * 32;
    const int scc2 = (t & 1) * 64;
    const int grow = row0 + sr;
    const bool rvalid = grow < M;
    const int h2b = wcl >> 5;

    f32x4 acc[4][4];
    #pragma unroll
    for (int i = 0; i < 4; ++i)
        #pragma unroll
        for (int j = 0; j < 4; ++j)
            acc[i][j] = (f32x4){0.f, 0.f, 0.f, 0.f};

    uint4 av[8];
    #pragma unroll
    for (int j = 0; j < 8; ++j) av[j] = make_uint4(0, 0, 0, 0);
    if (rvalid) {
        const uint4* ap = (const uint4*)(A + (size_t)grow * 512 + scc2);
        #pragma unroll
        for (int j = 0; j < 8; ++j) av[j] = ap[j];
    }
    uint4 bw0, bw1;
    {
        const uint4* bp = (const uint4*)(W3c + sr * 32 + scc);
        bw0 = bp[0]; bw1 = bp[1];
    }
    for (int it = 0; it < 4; ++it) {
        __syncthreads();
        #pragma unroll
        for (int j = 0; j < 8; ++j)
            *(uint4*)(msgS + sr * 136 + scc2 + j * 8) = av[j];
        *(uint4*)(Bs + sr * 68 + scc)     = bw0;
        *(uint4*)(Bs + sr * 68 + scc + 8) = bw1;
        __syncthreads();
        if (it + 1 < 4) {
            if (rvalid) {
                const uint4* ap = (const uint4*)(A + (size_t)grow * 512 + (it + 1) * 128 + scc2);
                #pragma unroll
                for (int j = 0; j < 8; ++j) av[j] = ap[j];
            }
            const uint4* bp = (const uint4*)(W3c + (it + 1) * 4096 + sr * 32 + scc);
            bw0 = bp[0]; bw1 = bp[1];
        }
        bf16x8 af2[2][4], bfr[4];
        #pragma unroll
        for (int g = 0; g < 2; ++g)
            #pragma unroll
            for (int f = 0; f < 4; ++f)
                af2[g][f] = *(const bf16x8*)(msgS + (wr + f * 16 + l16) * 136 + (h2b + g) * 32 + quad * 8);
        #pragma unroll
        for (int f = 0; f < 4; ++f)
            bfr[f] = *(const bf16x8*)(Bs + (wcl + f * 16 + l16) * 68 + quad * 8);
        #pragma unroll
        for (int fr = 0; fr < 4; ++fr)
            #pragma unroll
            for (int fc = 0; fc < 4; ++fc)
                acc[fr][fc] = __builtin_amdgcn_mfma_f32_16x16x32_bf16(
                    af2[fc >> 1][fr], bfr[fc], acc[fr][fc], 0, 0, 0);
    }
    __syncthreads();      // stage-1 msgS reads complete before gelu overwrite

    #pragma unroll
    for (int fr = 0; fr < 4; ++fr)
        #pragma unroll
        for (int reg = 0; reg < 4; ++reg) {
            int rl = wr + fr * 16 + quad * 4 + reg;
            #pragma unroll
            for (int fc = 0; fc < 4; ++fc) {
                int col = wcl + fc * 16 + l16;
                float v = acc[fr][fc][reg];
                float gl = 0.5f * v * (1.f + erff(v * 0.70710678118654752f));
                msgS[rl * 136 + col] = f2bf(gl);
            }
        }

    f32x4 acc2[4][4];
    #pragma unroll
    for (int i = 0; i < 4; ++i)
        #pragma unroll
        for (int j = 0; j < 4; ++j)
            acc2[i][j] = (f32x4){0.f, 0.f, 0.f, 0.f};
    uint4 pv[4];
    {
        const uint4* bp = (const uint4*)(AWt + (size_t)sr * 128 + half);
        #pragma unroll
        for (int j = 0; j < 4; ++j) pv[j] = bp[j];
    }
    for (int sup = 0; sup < 2; ++sup) {
        __syncthreads();
        #pragma unroll
        for (int j = 0; j < 4; ++j)
            *(uint4*)(Bs + sr * 68 + half + j * 8) = pv[j];
        __syncthreads();
        if (sup == 0) {
            const uint4* bp = (const uint4*)(AWt + (size_t)sr * 128 + 64 + half);
            #pragma unroll
            for (int j = 0; j < 4; ++j) pv[j] = bp[j];
        }
        #pragma unroll
        for (int it2 = 0; it2 < 2; ++it2) {
            const int it = sup * 2 + it2;
            bf16x8 af[4], bfr[4];
            #pragma unroll
            for (int f = 0; f < 4; ++f) {
                af[f]  = *(const bf16x8*)(msgS + (wr + f * 16 + l16) * 136 + it * 32 + quad * 8);
                bfr[f] = *(const bf16x8*)(Bs + (wcl + f * 16 + l16) * 68 + it2 * 32 + quad * 8);
            }
            #pragma unroll
            for (int fr = 0; fr < 4; ++fr)
                #pragma unroll
                for (int fc = 0; fc < 4; ++fc)
                    acc2[fr][fc] = __builtin_amdgcn_mfma_f32_16x16x32_bf16(
                        af[fr], bfr[fc], acc2[fr][fc], 0, 0, 0);
        }
    }

    const float gate = 1.f / (1.f + __expf(-skipv[0]));
    #pragma unroll
    for (int fr = 0; fr < 4; ++fr)
        #pragma unroll
        for (int reg = 0; reg < 4; ++reg) {
            int row = row0 + wr + fr * 16 + quad * 4 + reg;
            if (row >= M) continue;
            int hrow = rowmap[row];
            #pragma unroll
            for (int fc = 0; fc < 4; ++fc) {
                int col = wcl + fc * 16 + l16;
                float val = acc2[fr][fc][reg] + a_bias[col];
                float nv = gate * val + (1.f - gate) * bf2f((unsigned int)hres[(size_t)hrow * 128 + col]);
                out[(size_t)row * 128 + col] = nv;
            }
        }
}

extern "C" void kernel_launch(void* const* d_in, const int* in_sizes, int n_in,
                              void* d_out, int out_size, void* d_ws, size_t ws_size,
                              hipStream_t stream)
{
    const float* x      = (const float*)d_in[0];
    const float* proj_w = (const float*)d_in[1];
    const float* proj_b = (const float*)d_in[2];
    const float* bn_g   = (const float*)d_in[3];
    const float* bn_b   = (const float*)d_in[4];
    const float* q_w    = (const float*)d_in[5];
    const float* q_b    = (const float*)d_in[6];
    const float* k_w    = (const float*)d_in[7];
    const float* k_b    = (const float*)d_in[8];
    const float* v_w    = (const float*)d_in[9];
    const float* v_b    = (const float*)d_in[10];
    const float* a_w    = (const float*)d_in[11];
    const float* a_b    = (const float*)d_in[12];
    const float* skip   = (const float*)d_in[13];
    const float* a_rel  = (const float*)d_in[14];
    const float* m_rel  = (const float*)d_in[15];
    const float* p_rel  = (const float*)d_in[16];
    const int* edge_index = (const int*)d_in[17];
    const int* edge_type  = (const int*)d_in[18];
    const int* idx        = (const int*)d_in[19];
    float* out = (float*)d_out;

    const int N = NN, E = EE;
    float* ws = (float*)d_ws;
    size_t o = 0;
    float* stats  = ws + o;  o += 256;
    float* fbias  = ws + o;  o += 2 * 768;
    int* cnt  = (int*)(ws + o); o += NT4;
    int* off4 = (int*)(ws + o); o += NT4 + 1;
    int* fill = (int*)(ws + o); o += NT4;
    int* bsum = (int*)(ws + o); o += 1024;
    int* pack = (int*)(ws + o); o += E;
    unsigned short* x_bf   = (unsigned short*)(ws + o); o += (size_t)N * 64;  // scratch; reused by q1
    unsigned short* h_bf   = (unsigned short*)(ws + o); o += (size_t)N * 64;
    unsigned short* hn_bf  = (unsigned short*)(ws + o); o += (size_t)N * 64;
    unsigned short* h1_bf  = (unsigned short*)(ws + o); o += (size_t)N * 64;
    unsigned short* qkv_bf = (unsigned short*)(ws + o); o += (size_t)N * 384;
    unsigned short* agg_bf = (unsigned short*)(ws + o); o += (size_t)N * 256;
    unsigned short* wt_pa  = (unsigned short*)(ws + o); o += 3 * 16384 / 2;
    unsigned short* qkvw   = (unsigned short*)(ws + o); o += 2 * 98304 / 2;
    unsigned short* msg_wt = (unsigned short*)(ws + o); o += 2 * 65536 / 2;   // uses first 2*16384 now

    // idx-membership mask (50000 bytes) reuses cnt[0:12500) — dead after scan_block.
    unsigned char* mask = (unsigned char*)cnt;
    // q1 compact buffer [MOUT][512] reuses x_bf region.
    unsigned short* q1 = x_bf;   // 10000*512 shorts = 5.12M <= N*128 shorts

    const int NB4 = (NT4 + 255) / 256;          // 782
    const int g = (N + 127) / 128;              // 391

    // 1) prep: weights (compact msg), zero cnt/stats
    prep_kernel<<<1088 + NB4, 256, 0, stream>>>(
        proj_w, a_w, q_w, q_b, a_rel, k_w, k_b, v_w, v_b, m_rel, p_rel,
        wt_pa, qkvw, fbias, msg_wt, cnt, stats);

    // 2-5) CSR build; scan_add zeroes mask region (cnt dead), scatter sets mask
    hist_kernel<<<(E + 255) / 256, 256, 0, stream>>>(edge_index, edge_type, cnt, E);
    scan_block_kernel<<<NB4, 256, 0, stream>>>(cnt, off4, bsum, NT4);
    scan_add_kernel<<<NB4, 256, 0, stream>>>(off4, bsum, fill, cnt, NT4, E);
    scatter_kernel<<<(E + 255) / 256, 256, 0, stream>>>(edge_index, edge_type, fill,
                                                        pack, idx, mask, MOUT, E);

    // 6) proj GEMM + BN stats (A = x f32, cast in-register)
    projstats_kernel<<<g, 256, 0, stream>>>(x, wt_pa, proj_b, h_bf, stats, N);

    // 7) BN apply + qkv0 (64-col B staging)
    bnqkv_kernel<<<g, 256, 0, stream>>>(h_bf, stats, bn_g, bn_b, qkvw, fbias,
                                        hn_bf, qkv_bf, N);

    // 8) attention layer 0 (all nodes; pair-processing, 16B kv chunks)
    agg_fused_kernel<<<(N + 3) / 4, 256, 0, stream>>>(qkv_bf, qkv_bf, 768,
                                                      off4, pack, nullptr, agg_bf, N);

    // 9) MLP0 (block-diag stage 1, 64-col stages 2/3) + residual + qkv1 KV
    mlpqkv_kernel<<<g, 256, 0, stream>>>(agg_bf, msg_wt, wt_pa + 16384, a_b, skip,
                                         hn_bf, qkvw + 98304, fbias + 768,
                                         mask, h1_bf, qkv_bf, N);

    // 9.5) compact layer-1 q for the idx rows only (64-col staging)
    q1_kernel<<<(MOUT + 127) / 128, 256, 0, stream>>>(h1_bf, idx, qkvw + 98304,
                                                      fbias + 768, q1, MOUT);

    // 10) attention layer 1 (idx rows; q from compact q1, kv gathered from qkv)
    agg_fused_kernel<<<(MOUT + 3) / 4, 256, 0, stream>>>(qkv_bf, q1, 512,
                                                         off4, pack, idx, agg_bf, MOUT);

    // 11) MLP1 (block-diag stage 1, 64-col stage 2) + residual -> out
    mlp1_kernel<<<(MOUT + 127) / 128, 256, 0, stream>>>(agg_bf, msg_wt + 16384,
                                                        wt_pa + 2 * 16384, a_b + 128,
                                                        skip + 1, h1_bf, idx, out, MOUT);
}

// Round 10
// 427.320 us; speedup vs baseline: 1.0887x; 1.0887x over previous
//
#include <hip/hip_runtime.h>
#include <math.h>

#define NN 50000
#define EE 600000
#define MOUT 10000
#define DEGCAP 384
#define NT4 (NN * 4)

typedef short bf16x8 __attribute__((ext_vector_type(8)));
typedef float f32x4 __attribute__((ext_vector_type(4)));

__device__ __forceinline__ unsigned short f2bf(float x) {
    unsigned int u = __float_as_uint(x);
    u = (u + 0x7FFFu + ((u >> 16) & 1u)) >> 16;
    return (unsigned short)u;
}
__device__ __forceinline__ float bf2f(unsigned int b) {
    return __uint_as_float(b << 16);
}
__device__ __forceinline__ uint4 pack8bf(float4 a, float4 b) {
    uint4 r;
    r.x = (unsigned int)f2bf(a.x) | ((unsigned int)f2bf(a.y) << 16);
    r.y = (unsigned int)f2bf(a.z) | ((unsigned int)f2bf(a.w) << 16);
    r.z = (unsigned int)f2bf(b.x) | ((unsigned int)f2bf(b.y) << 16);
    r.w = (unsigned int)f2bf(b.z) | ((unsigned int)f2bf(b.w) << 16);
    return r;
}

// ============ merged weight prep + CSR/stats zeroing ============
// qkv weight rows 512..767 PERMUTED into 16B chunks (k[4t..4t+3], v[4t..4t+3]);
// qrel rows pre-scaled by p_rel/sqrt(32).
// msg weight stored COMPACT block-diagonal: msg_wt2[(l*4+r)*4096 + n*32 + d]
//   = m_rel[l][r][h=n>>5][d][e=n&31].
__global__ __launch_bounds__(256) void prep_kernel(
    const float* __restrict__ proj_w, const float* __restrict__ a_w,
    const float* __restrict__ q_w, const float* __restrict__ q_b,
    const float* __restrict__ a_rel,
    const float* __restrict__ k_w, const float* __restrict__ k_b,
    const float* __restrict__ v_w, const float* __restrict__ v_b,
    const float* __restrict__ m_rel, const float* __restrict__ p_rel,
    unsigned short* __restrict__ wt_pa, unsigned short* __restrict__ qkvw,
    float* __restrict__ fbias, unsigned short* __restrict__ msg_wt,
    int* __restrict__ cnt, float* __restrict__ stats)
{
    const int b = blockIdx.x, t = threadIdx.x;
    if (b < 192) {                       // proj^T, a_w0^T, a_w1^T
        int wi = b >> 6;
        int flat = (b & 63) * 256 + t;
        int n = flat >> 7, c = flat & 127;
        const float* src = (wi == 0) ? proj_w : (wi == 1) ? a_w : a_w + 16384;
        wt_pa[(size_t)wi * 16384 + n * 128 + c] = f2bf(src[c * 128 + n]);
    } else if (b < 960) {                // fused qkv weight [768][128] per layer
        int q = b - 192;
        int l = q >= 384 ? 1 : 0;
        int flat = (q - l * 384) * 256 + t;
        int nrow = flat >> 7, c = flat & 127;
        unsigned short* wt = qkvw + (size_t)l * 98304;
        float* fb = fbias + l * 768;
        if (nrow < 512) {
            int r = nrow >> 7, hh = (nrow >> 5) & 3, d = nrow & 31;
            float prl = p_rel[l * 16 + r * 4 + hh] * 0.17677669529663687f;
            const float* qwc = q_w + (size_t)l * 16384 + c * 128 + hh * 32;
            const float* ar  = a_rel + (size_t)(l * 4 + r) * 4096 + hh * 1024 + d * 32;
            float s = 0.f;
            #pragma unroll 8
            for (int e = 0; e < 32; ++e) s += qwc[e] * ar[e];
            wt[(size_t)nrow * 128 + c] = f2bf(s * prl);
            if (c == 0) {
                const float* qb = q_b + l * 128 + hh * 32;
                float bb = 0.f;
                #pragma unroll 8
                for (int e = 0; e < 32; ++e) bb += qb[e] * ar[e];
                fb[nrow] = bb * prl;
            }
        } else {                         // k/v 16B-chunk rows: t-th chunk = k[4t..4t+3], v[4t..4t+3]
            int j = nrow - 512;
            int tt = j >> 3, s = j & 7;
            int col = 4 * tt + (s & 3);
            const float* w  = (s < 4) ? k_w : v_w;
            const float* bb = (s < 4) ? k_b : v_b;
            wt[(size_t)nrow * 128 + c] = f2bf(w[(size_t)l * 16384 + c * 128 + col]);
            if (c == 0) fb[nrow] = bb[l * 128 + col];
        }
    } else if (b < 1088) {               // compact msg weight: 2 layers x 4 rel x [128 n][32 d]
        int q = b - 960;
        int l = q >= 64 ? 1 : 0;
        int flat = (q - l * 64) * 256 + t;     // 0 .. 16383
        int r = flat >> 12, rem = flat & 4095;
        int n = rem >> 5, d = rem & 31;
        float val = m_rel[(size_t)(l * 4 + r) * 4096 + (n >> 5) * 1024 + d * 32 + (n & 31)];
        msg_wt[(size_t)l * 16384 + r * 4096 + n * 32 + d] = f2bf(val);
    } else {                             // zero cnt + stats
        int i = (b - 1088) * 256 + t;
        if (i < NT4) cnt[i] = 0;
        if (i < 256) stats[i] = 0.f;
    }
}

// ============ CSR build ============
__global__ __launch_bounds__(256) void hist_kernel(const int* __restrict__ ei,
    const int* __restrict__ et, int* __restrict__ cnt, int E)
{
    int e = blockIdx.x * 256 + threadIdx.x;
    if (e < E) atomicAdd(&cnt[ei[E + e] * 4 + et[e]], 1);
}

__global__ __launch_bounds__(256) void scan_block_kernel(const int* __restrict__ cnt,
    int* __restrict__ excl, int* __restrict__ bsum, int n)
{
    __shared__ int tmp[256];
    int i = blockIdx.x * 256 + threadIdx.x;
    int v = (i < n) ? cnt[i] : 0;
    tmp[threadIdx.x] = v;
    __syncthreads();
    for (int ofs = 1; ofs < 256; ofs <<= 1) {
        int t = (threadIdx.x >= ofs) ? tmp[threadIdx.x - ofs] : 0;
        __syncthreads();
        tmp[threadIdx.x] += t;
        __syncthreads();
    }
    if (i < n) excl[i] = tmp[threadIdx.x] - v;
    if (threadIdx.x == 255) bsum[blockIdx.x] = tmp[255];
}

// per-block prefix over bsum; ALSO zeroes the idx-mask region (reuses dead cnt[0:12500))
__global__ __launch_bounds__(256) void scan_add_kernel(int* __restrict__ excl,
    const int* __restrict__ bsum, int* __restrict__ fill,
    int* __restrict__ maskz, int n, int total)
{
    __shared__ int red[256];
    const int b = blockIdx.x;
    int partial = 0;
    for (int j = threadIdx.x; j < b; j += 256) partial += bsum[j];
    red[threadIdx.x] = partial;
    __syncthreads();
    for (int ofs = 128; ofs > 0; ofs >>= 1) {
        if (threadIdx.x < ofs) red[threadIdx.x] += red[threadIdx.x + ofs];
        __syncthreads();
    }
    int prefix = red[0];
    int i = b * 256 + threadIdx.x;
    if (i < n) {
        int o = excl[i] + prefix;
        excl[i] = o;
        fill[i] = o;
    }
    if (i < 12500) maskz[i] = 0;         // cnt region is dead after scan_block
    if (b == 0 && threadIdx.x == 0) excl[n] = total;
}

// scatter + idx-membership mask set (mask lives in old cnt region)
__global__ __launch_bounds__(256) void scatter_kernel(const int* __restrict__ ei,
    const int* __restrict__ et, int* __restrict__ fill, int* __restrict__ pack,
    const int* __restrict__ idxp, unsigned char* __restrict__ mask, int Mo, int E)
{
    int e = blockIdx.x * 256 + threadIdx.x;
    if (e >= E) return;
    int seg = ei[E + e] * 4 + et[e];
    int p = atomicAdd(&fill[seg], 1);
    pack[p] = ei[e];
    if (e < Mo) mask[idxp[e]] = 1;
}

// ============ proj GEMM + BN-stats epilogue, A loaded as f32 and cast in-register ============
__global__ __launch_bounds__(256) void projstats_kernel(
    const float* __restrict__ X, const unsigned short* __restrict__ Wt,
    const float* __restrict__ bias, unsigned short* __restrict__ Cb,
    float* __restrict__ stats, int M)
{
    __shared__ unsigned short As[128 * 40];
    __shared__ unsigned short Bs[128 * 40];
    const int t = threadIdx.x;
    const int wave = t >> 6, lane = t & 63;
    const int quad = lane >> 4, l16 = lane & 15;
    const int row0 = blockIdx.x * 128;
    const int wr = (wave & 1) * 64, wc = (wave >> 1) * 64;
    const int sr = t >> 1, sc = (t & 1) * 16;
    const int grow = row0 + sr;

    f32x4 acc[4][4];
    #pragma unroll
    for (int i = 0; i < 4; ++i)
        #pragma unroll
        for (int j = 0; j < 4; ++j)
            acc[i][j] = (f32x4){0.f, 0.f, 0.f, 0.f};

    uint4 av0 = make_uint4(0,0,0,0), av1 = av0, bv0, bv1;
    if (grow < M) {
        const float4* ap = (const float4*)(X + (size_t)grow * 128 + sc);
        av0 = pack8bf(ap[0], ap[1]);
        av1 = pack8bf(ap[2], ap[3]);
    }
    {
        const uint4* bp = (const uint4*)(Wt + (size_t)sr * 128 + sc);
        bv0 = bp[0]; bv1 = bp[1];
    }
    for (int it = 0; it < 4; ++it) {
        __syncthreads();
        *(uint4*)(As + sr * 40 + sc)     = av0;
        *(uint4*)(As + sr * 40 + sc + 8) = av1;
        *(uint4*)(Bs + sr * 40 + sc)     = bv0;
        *(uint4*)(Bs + sr * 40 + sc + 8) = bv1;
        __syncthreads();
        if (it + 1 < 4) {
            int kb = (it + 1) * 32;
            if (grow < M) {
                const float4* ap = (const float4*)(X + (size_t)grow * 128 + kb + sc);
                av0 = pack8bf(ap[0], ap[1]);
                av1 = pack8bf(ap[2], ap[3]);
            }
            const uint4* bp = (const uint4*)(Wt + (size_t)sr * 128 + kb + sc);
            bv0 = bp[0]; bv1 = bp[1];
        }
        bf16x8 af[4], bfr[4];
        #pragma unroll
        for (int f = 0; f < 4; ++f) {
            af[f]  = *(const bf16x8*)(As + (wr + f * 16 + l16) * 40 + quad * 8);
            bfr[f] = *(const bf16x8*)(Bs + (wc + f * 16 + l16) * 40 + quad * 8);
        }
        #pragma unroll
        for (int fr = 0; fr < 4; ++fr)
            #pragma unroll
            for (int fc = 0; fc < 4; ++fc)
                acc[fr][fc] = __builtin_amdgcn_mfma_f32_16x16x32_bf16(
                    af[fr], bfr[fc], acc[fr][fc], 0, 0, 0);
    }

    #pragma unroll
    for (int fc = 0; fc < 4; ++fc) {
        const int col = wc + fc * 16 + l16;
        const float bv = bias[col];
        float s = 0.f, s2 = 0.f;
        #pragma unroll
        for (int fr = 0; fr < 4; ++fr)
            #pragma unroll
            for (int reg = 0; reg < 4; ++reg) {
                int row = row0 + wr + fr * 16 + quad * 4 + reg;
                float val = acc[fr][fc][reg] + bv;
                if (row < M) {
                    Cb[(size_t)row * 128 + col] = f2bf(val);
                    s += val; s2 += val * val;
                }
            }
        s  += __shfl_xor(s, 16);  s  += __shfl_xor(s, 32);
        s2 += __shfl_xor(s2, 16); s2 += __shfl_xor(s2, 32);
        if (quad == 0) {
            atomicAdd(&stats[col], s);
            atomicAdd(&stats[128 + col], s2);
        }
    }
}

// ============ BN-apply + qkv0 GEMM, CHUNK-SPLIT: gridDim.y=3, 2 col-chunks per block ============
__global__ __launch_bounds__(256) void bnqkv_kernel(
    const unsigned short* __restrict__ hb, const float* __restrict__ stats,
    const float* __restrict__ gamma, const float* __restrict__ beta,
    const unsigned short* __restrict__ qkvw, const float* __restrict__ fbias,
    unsigned short* __restrict__ hn, unsigned short* __restrict__ qkv, int M)
{
    __shared__ unsigned short hS[128 * 136];
    __shared__ unsigned short Bs[128 * 40];
    __shared__ float mulS[128], addS[128];
    const int t = threadIdx.x;
    const int row0 = blockIdx.x * 128;
    const int ch0 = blockIdx.y * 2;
    if (t < 128) {
        float invN = 1.f / 50000.f;
        float mu = stats[t] * invN;
        float var = stats[128 + t] * invN - mu * mu;
        float ml = rsqrtf(var + 1e-5f) * gamma[t];
        mulS[t] = ml;
        addS[t] = beta[t] - mu * ml;
    }
    __syncthreads();
    #pragma unroll
    for (int u = 0; u < 8; ++u) {
        int li = t + u * 256;                 // uint4 index; 16 per row
        int row = li >> 4, c0 = (li & 15) * 8;
        uint4 pk = make_uint4(0, 0, 0, 0);
        if (row0 + row < M)
            pk = ((const uint4*)(hb + (size_t)(row0 + row) * 128))[li & 15];
        unsigned int w[4] = {pk.x, pk.y, pk.z, pk.w};
        uint4 o;
        unsigned int ov[4];
        #pragma unroll
        for (int g = 0; g < 4; ++g) {
            int c = c0 + g * 2;
            float a0 = bf2f(w[g] & 0xFFFFu) * mulS[c]     + addS[c];
            float a1 = bf2f(w[g] >> 16)     * mulS[c + 1] + addS[c + 1];
            ov[g] = (unsigned int)f2bf(a0) | ((unsigned int)f2bf(a1) << 16);
        }
        o.x = ov[0]; o.y = ov[1]; o.z = ov[2]; o.w = ov[3];
        *(uint4*)(hS + row * 136 + c0) = o;
        if (blockIdx.y == 0 && row0 + row < M)
            ((uint4*)(hn + (size_t)(row0 + row) * 128))[li & 15] = o;
    }
    __syncthreads();

    const int wave = t >> 6, lane = t & 63;
    const int quad = lane >> 4, l16 = lane & 15;
    const int wr = (wave & 1) * 64, wcl = (wave >> 1) * 64;
    const int sr = t >> 1, scc = (t & 1) * 16;

    // weight prefetch registers for (ch=ch0, it=0)
    uint4 pv0, pv1;
    {
        const uint4* bp = (const uint4*)(qkvw + (size_t)(ch0 * 128 + sr) * 128 + scc);
        pv0 = bp[0]; pv1 = bp[1];
    }
    for (int ch = ch0; ch < ch0 + 2; ++ch) {
        f32x4 acc[4][4];
        #pragma unroll
        for (int i = 0; i < 4; ++i)
            #pragma unroll
            for (int j = 0; j < 4; ++j)
                acc[i][j] = (f32x4){0.f, 0.f, 0.f, 0.f};
        for (int it = 0; it < 4; ++it) {
            __syncthreads();
            *(uint4*)(Bs + sr * 40 + scc)     = pv0;
            *(uint4*)(Bs + sr * 40 + scc + 8) = pv1;
            __syncthreads();
            int nit = it + 1, nch = ch;
            if (nit == 4) { nit = 0; ++nch; }
            if (nch < ch0 + 2) {
                const uint4* bp = (const uint4*)(qkvw + (size_t)(nch * 128 + sr) * 128 + nit * 32 + scc);
                pv0 = bp[0]; pv1 = bp[1];
            }
            bf16x8 af[4], bfr[4];
            #pragma unroll
            for (int f = 0; f < 4; ++f) {
                af[f]  = *(const bf16x8*)(hS + (wr + f * 16 + l16) * 136 + it * 32 + quad * 8);
                bfr[f] = *(const bf16x8*)(Bs + (wcl + f * 16 + l16) * 40 + quad * 8);
            }
            #pragma unroll
            for (int fr = 0; fr < 4; ++fr)
                #pragma unroll
                for (int fc = 0; fc < 4; ++fc)
                    acc[fr][fc] = __builtin_amdgcn_mfma_f32_16x16x32_bf16(
                        af[fr], bfr[fc], acc[fr][fc], 0, 0, 0);
        }
        float b4[4];
        #pragma unroll
        for (int fc = 0; fc < 4; ++fc)
            b4[fc] = fbias[ch * 128 + wcl + fc * 16 + l16];
        #pragma unroll
        for (int fr = 0; fr < 4; ++fr)
            #pragma unroll
            for (int reg = 0; reg < 4; ++reg) {
                int row = row0 + wr + fr * 16 + quad * 4 + reg;
                if (row >= M) continue;
                #pragma unroll
                for (int fc = 0; fc < 4; ++fc) {
                    int col = ch * 128 + wcl + fc * 16 + l16;
                    qkv[(size_t)row * 768 + col] = f2bf(acc[fr][fc][reg] + b4[fc]);
                }
            }
    }
}

// ============ fused attention: per-node wave, PAIR processing (2 edges across wave halves) ====
__global__ __launch_bounds__(256) void agg_fused_kernel(
    const unsigned short* __restrict__ qkv,
    const unsigned short* __restrict__ qbuf, int qpitch,
    const int* __restrict__ off4, const int* __restrict__ pack,
    const int* __restrict__ rowmap, unsigned short* __restrict__ aggb, int count)
{
    __shared__ int spack[4][DEGCAP];
    const int wv = threadIdx.x >> 6;
    const int lane = threadIdx.x & 63;
    const int l32 = lane & 31;
    const int hi = lane >> 5;
    const int unit = blockIdx.x * 4 + wv;
    if (unit >= count) return;                 // no __syncthreads in this kernel
    const int node = rowmap ? __builtin_amdgcn_readfirstlane(rowmap[unit]) : unit;

    // q dims [4*l32 .. 4*l32+3] per run (both halves need the same dims)
    const uint2* qrow = (const uint2*)(qbuf + (size_t)unit * qpitch);
    uint2 quv[4];
    #pragma unroll
    for (int r = 0; r < 4; ++r) quv[r] = qrow[r * 32 + l32];

    int off_r[5];
    #pragma unroll
    for (int i = 0; i < 5; ++i)
        off_r[i] = __builtin_amdgcn_readfirstlane(off4[node * 4 + i]);
    const int beg = off_r[0];
    const int deg = off_r[4] - beg;
    const bool cached = deg <= DEGCAP;

    if (cached) {
        for (int i = lane; i < deg; i += 64) spack[wv][i] = pack[beg + i];
        asm volatile("s_waitcnt vmcnt(0) lgkmcnt(0)" ::: "memory");
    }

    uint2 outw[4];
    #pragma unroll
    for (int r = 0; r < 4; ++r) {
        float q0 = bf2f(quv[r].x & 0xFFFFu), q1 = bf2f(quv[r].x >> 16);
        float q2 = bf2f(quv[r].y & 0xFFFFu), q3 = bf2f(quv[r].y >> 16);
        float den = 0.f, a0 = 0.f, a1 = 0.f, a2 = 0.f, a3 = 0.f;

        if (cached) {
            const int rb = off_r[r] - beg, re = off_r[r + 1] - beg;
            for (int i = rb; i < re; i += 4) {
                int i0 = i + hi;      if (i0 >= re) i0 = re - 1;
                int i1 = i + 2 + hi;  if (i1 >= re) i1 = re - 1;
                int s0 = spack[wv][i0], s1 = spack[wv][i1];
                uint4 kv0 = *(const uint4*)(qkv + (size_t)s0 * 768 + 512 + l32 * 8);
                uint4 kv1 = *(const uint4*)(qkv + (size_t)s1 * 768 + 512 + l32 * 8);
                {
                    float p = q0 * bf2f(kv0.x & 0xFFFFu) + q1 * bf2f(kv0.x >> 16)
                            + q2 * bf2f(kv0.y & 0xFFFFu) + q3 * bf2f(kv0.y >> 16);
                    p += __shfl_xor(p, 1); p += __shfl_xor(p, 2); p += __shfl_xor(p, 4);
                    float e = __expf(fminf(fmaxf(p, -80.f), 80.f));
                    if (i + hi >= re) e = 0.f;
                    den += e;
                    a0 += e * bf2f(kv0.z & 0xFFFFu); a1 += e * bf2f(kv0.z >> 16);
                    a2 += e * bf2f(kv0.w & 0xFFFFu); a3 += e * bf2f(kv0.w >> 16);
                }
                {
                    float p = q0 * bf2f(kv1.x & 0xFFFFu) + q1 * bf2f(kv1.x >> 16)
                            + q2 * bf2f(kv1.y & 0xFFFFu) + q3 * bf2f(kv1.y >> 16);
                    p += __shfl_xor(p, 1); p += __shfl_xor(p, 2); p += __shfl_xor(p, 4);
                    float e = __expf(fminf(fmaxf(p, -80.f), 80.f));
                    if (i + 2 + hi >= re) e = 0.f;
                    den += e;
                    a0 += e * bf2f(kv1.z & 0xFFFFu); a1 += e * bf2f(kv1.z >> 16);
                    a2 += e * bf2f(kv1.w & 0xFFFFu); a3 += e * bf2f(kv1.w >> 16);
                }
            }
        } else {   // giant-degree fallback: pair walk straight from pack
            const int pe_end = off_r[r + 1];
            for (int pp = off_r[r]; pp < pe_end; pp += 2) {
                int pe = pp + hi; if (pe >= pe_end) pe = pe_end - 1;
                int src = pack[pe];
                uint4 kv = *(const uint4*)(qkv + (size_t)src * 768 + 512 + l32 * 8);
                float p = q0 * bf2f(kv.x & 0xFFFFu) + q1 * bf2f(kv.x >> 16)
                        + q2 * bf2f(kv.y & 0xFFFFu) + q3 * bf2f(kv.y >> 16);
                p += __shfl_xor(p, 1); p += __shfl_xor(p, 2); p += __shfl_xor(p, 4);
                float e = __expf(fminf(fmaxf(p, -80.f), 80.f));
                if (pp + hi >= pe_end) e = 0.f;
                den += e;
                a0 += e * bf2f(kv.z & 0xFFFFu); a1 += e * bf2f(kv.z >> 16);
                a2 += e * bf2f(kv.w & 0xFFFFu); a3 += e * bf2f(kv.w >> 16);
            }
        }
        // merge the two halves (lane l and l+32 hold the same dims, different edges)
        den += __shfl_xor(den, 32);
        a0  += __shfl_xor(a0, 32);
        a1  += __shfl_xor(a1, 32);
        a2  += __shfl_xor(a2, 32);
        a3  += __shfl_xor(a3, 32);
        float inv = den > 0.f ? 1.f / den : 0.f;
        outw[r].x = (unsigned int)f2bf(a0 * inv) | ((unsigned int)f2bf(a1 * inv) << 16);
        outw[r].y = (unsigned int)f2bf(a2 * inv) | ((unsigned int)f2bf(a3 * inv) << 16);
    }
    if (hi == 0) {
        uint2* op = (uint2*)(aggb + (size_t)unit * 512);
        #pragma unroll
        for (int r = 0; r < 4; ++r) op[r * 32 + l32] = outw[r];
    }
}

// ============ layer-0 MLP + qkv1-kv (block-diagonal stage 1, K=32 per head) ============
__global__ __launch_bounds__(256) void mlpqkv_kernel(
    const unsigned short* __restrict__ A, const unsigned short* __restrict__ W3c,
    const unsigned short* __restrict__ AWt, const float* __restrict__ a_bias,
    const float* __restrict__ skipv, const unsigned short* __restrict__ hres,
    const unsigned short* __restrict__ qkvw1, const float* __restrict__ fbias1,
    const unsigned char* __restrict__ mask,
    unsigned short* __restrict__ h1, unsigned short* __restrict__ qkv, int M)
{
    __shared__ unsigned short Bs[128 * 40];
    __shared__ unsigned short msgS[128 * 136];
    const int t = threadIdx.x;
    const int wave = t >> 6, lane = t & 63;
    const int quad = lane >> 4, l16 = lane & 15;
    const int row0 = blockIdx.x * 128;
    const int wr = (wave & 1) * 64, wcl = (wave >> 1) * 64;
    const int sr = t >> 1, scc = (t & 1) * 16;
    const int scc2 = (t & 1) * 64;
    const int grow = row0 + sr;
    const bool rvalid = grow < M;
    const int h2b = wcl >> 5;            // first head of this wave's output cols (0 or 2)

    // ---- stage 1: block-diagonal, 4 its (it == relation r), K=32 per output head ----
    f32x4 acc[4][4];
    #pragma unroll
    for (int i = 0; i < 4; ++i)
        #pragma unroll
        for (int j = 0; j < 4; ++j)
            acc[i][j] = (f32x4){0.f, 0.f, 0.f, 0.f};

    uint4 av[8];
    #pragma unroll
    for (int j = 0; j < 8; ++j) av[j] = make_uint4(0, 0, 0, 0);
    if (rvalid) {
        const uint4* ap = (const uint4*)(A + (size_t)grow * 512 + scc2);
        #pragma unroll
        for (int j = 0; j < 8; ++j) av[j] = ap[j];
    }
    uint4 bw0, bw1;
    {
        const uint4* bp = (const uint4*)(W3c + sr * 32 + scc);
        bw0 = bp[0]; bw1 = bp[1];
    }
    for (int it = 0; it < 4; ++it) {
        __syncthreads();
        #pragma unroll
        for (int j = 0; j < 8; ++j)
            *(uint4*)(msgS + sr * 136 + scc2 + j * 8) = av[j];
        *(uint4*)(Bs + sr * 40 + scc)     = bw0;
        *(uint4*)(Bs + sr * 40 + scc + 8) = bw1;
        __syncthreads();
        if (it + 1 < 4) {
            if (rvalid) {
                const uint4* ap = (const uint4*)(A + (size_t)grow * 512 + (it + 1) * 128 + scc2);
                #pragma unroll
                for (int j = 0; j < 8; ++j) av[j] = ap[j];
            }
            const uint4* bp = (const uint4*)(W3c + (it + 1) * 4096 + sr * 32 + scc);
            bw0 = bp[0]; bw1 = bp[1];
        }
        bf16x8 af2[2][4], bfr[4];
        #pragma unroll
        for (int g = 0; g < 2; ++g)
            #pragma unroll
            for (int f = 0; f < 4; ++f)
                af2[g][f] = *(const bf16x8*)(msgS + (wr + f * 16 + l16) * 136 + (h2b + g) * 32 + quad * 8);
        #pragma unroll
        for (int f = 0; f < 4; ++f)
            bfr[f] = *(const bf16x8*)(Bs + (wcl + f * 16 + l16) * 40 + quad * 8);
        #pragma unroll
        for (int fr = 0; fr < 4; ++fr)
            #pragma unroll
            for (int fc = 0; fc < 4; ++fc)
                acc[fr][fc] = __builtin_amdgcn_mfma_f32_16x16x32_bf16(
                    af2[fc >> 1][fr], bfr[fc], acc[fr][fc], 0, 0, 0);
    }
    __syncthreads();      // all stage-1 msgS reads complete before gelu overwrite

    // gelu -> msgS
    #pragma unroll
    for (int fr = 0; fr < 4; ++fr)
        #pragma unroll
        for (int reg = 0; reg < 4; ++reg) {
            int rl = wr + fr * 16 + quad * 4 + reg;
            #pragma unroll
            for (int fc = 0; fc < 4; ++fc) {
                int col = wcl + fc * 16 + l16;
                float v = acc[fr][fc][reg];
                float gl = 0.5f * v * (1.f + erff(v * 0.70710678118654752f));
                msgS[rl * 136 + col] = f2bf(gl);
            }
        }

    // stage 2: K = 128 from msgS vs AWt (weights prefetched)
    f32x4 acc2[4][4];
    #pragma unroll
    for (int i = 0; i < 4; ++i)
        #pragma unroll
        for (int j = 0; j < 4; ++j)
            acc2[i][j] = (f32x4){0.f, 0.f, 0.f, 0.f};
    uint4 pv0, pv1;
    {
        const uint4* bp = (const uint4*)(AWt + (size_t)sr * 128 + scc);
        pv0 = bp[0]; pv1 = bp[1];
    }
    for (int it = 0; it < 4; ++it) {
        __syncthreads();
        *(uint4*)(Bs + sr * 40 + scc)     = pv0;
        *(uint4*)(Bs + sr * 40 + scc + 8) = pv1;
        __syncthreads();
        if (it + 1 < 4) {
            const uint4* bp = (const uint4*)(AWt + (size_t)sr * 128 + (it + 1) * 32 + scc);
            pv0 = bp[0]; pv1 = bp[1];
        } else {       // prefetch stage-3 (ch=4, it=0)
            const uint4* bp = (const uint4*)(qkvw1 + (size_t)(4 * 128 + sr) * 128 + scc);
            pv0 = bp[0]; pv1 = bp[1];
        }
        bf16x8 af[4], bfr[4];
        #pragma unroll
        for (int f = 0; f < 4; ++f) {
            af[f]  = *(const bf16x8*)(msgS + (wr + f * 16 + l16) * 136 + it * 32 + quad * 8);
            bfr[f] = *(const bf16x8*)(Bs + (wcl + f * 16 + l16) * 40 + quad * 8);
        }
        #pragma unroll
        for (int fr = 0; fr < 4; ++fr)
            #pragma unroll
            for (int fc = 0; fc < 4; ++fc)
                acc2[fr][fc] = __builtin_amdgcn_mfma_f32_16x16x32_bf16(
                    af[fr], bfr[fc], acc2[fr][fc], 0, 0, 0);
    }

    const float gate = 1.f / (1.f + __expf(-skipv[0]));
    __syncthreads();                            // all stage-2 msgS reads complete
    #pragma unroll
    for (int fr = 0; fr < 4; ++fr)
        #pragma unroll
        for (int reg = 0; reg < 4; ++reg) {
            int rl = wr + fr * 16 + quad * 4 + reg;
            int row = row0 + rl;
            const bool rv = row < M;
            const bool mw = rv && mask[row];    // h1 only ever read at idx rows
            #pragma unroll
            for (int fc = 0; fc < 4; ++fc) {
                int col = wcl + fc * 16 + l16;
                float val = acc2[fr][fc][reg] + a_bias[col];
                float nv = val;
                if (rv) {
                    unsigned int hu = hres[(size_t)row * 128 + col];
                    nv = gate * val + (1.f - gate) * bf2f(hu);
                    if (mw) h1[(size_t)row * 128 + col] = f2bf(nv);
                }
                msgS[rl * 136 + col] = f2bf(nv);   // h1 tile for stage 3
            }
        }

    // stage 3: qkv1 KV ONLY = h1 @ qkvw1^T cols 512..767 (K = 128 from msgS)
    for (int ch = 4; ch < 6; ++ch) {
        f32x4 acc3[4][4];
        #pragma unroll
        for (int i = 0; i < 4; ++i)
            #pragma unroll
            for (int j = 0; j < 4; ++j)
                acc3[i][j] = (f32x4){0.f, 0.f, 0.f, 0.f};
        for (int it = 0; it < 4; ++it) {
            __syncthreads();
            *(uint4*)(Bs + sr * 40 + scc)     = pv0;
            *(uint4*)(Bs + sr * 40 + scc + 8) = pv1;
            __syncthreads();
            int nit = it + 1, nch = ch;
            if (nit == 4) { nit = 0; ++nch; }
            if (nch < 6) {
                const uint4* bp = (const uint4*)(qkvw1 + (size_t)(nch * 128 + sr) * 128 + nit * 32 + scc);
                pv0 = bp[0]; pv1 = bp[1];
            }
            bf16x8 af[4], bfr[4];
            #pragma unroll
            for (int f = 0; f < 4; ++f) {
                af[f]  = *(const bf16x8*)(msgS + (wr + f * 16 + l16) * 136 + it * 32 + quad * 8);
                bfr[f] = *(const bf16x8*)(Bs + (wcl + f * 16 + l16) * 40 + quad * 8);
            }
            #pragma unroll
            for (int fr = 0; fr < 4; ++fr)
                #pragma unroll
                for (int fc = 0; fc < 4; ++fc)
                    acc3[fr][fc] = __builtin_amdgcn_mfma_f32_16x16x32_bf16(
                        af[fr], bfr[fc], acc3[fr][fc], 0, 0, 0);
        }
        float b4[4];
        #pragma unroll
        for (int fc = 0; fc < 4; ++fc)
            b4[fc] = fbias1[ch * 128 + wcl + fc * 16 + l16];
        #pragma unroll
        for (int fr = 0; fr < 4; ++fr)
            #pragma unroll
            for (int reg = 0; reg < 4; ++reg) {
                int row = row0 + wr + fr * 16 + quad * 4 + reg;
                if (row >= M) continue;
                #pragma unroll
                for (int fc = 0; fc < 4; ++fc) {
                    int col = ch * 128 + wcl + fc * 16 + l16;
                    qkv[(size_t)row * 768 + col] = f2bf(acc3[fr][fc][reg] + b4[fc]);
                }
            }
    }
}

// ============ compact layer-1 q, CHUNK-SPLIT: gridDim.y=4, one col-chunk per block ============
__global__ __launch_bounds__(256) void q1_kernel(
    const unsigned short* __restrict__ h1, const int* __restrict__ idxp,
    const unsigned short* __restrict__ qkvw1, const float* __restrict__ fbias1,
    unsigned short* __restrict__ q1, int M)
{
    __shared__ unsigned short hS[128 * 136];
    __shared__ unsigned short Bs[128 * 40];
    const int t = threadIdx.x;
    const int row0 = blockIdx.x * 128;
    const int ch = blockIdx.y;
    #pragma unroll
    for (int u = 0; u < 8; ++u) {
        int li = t + u * 256;                 // uint4 index; 16 per row
        int row = li >> 4, c = li & 15;
        uint4 pk = make_uint4(0, 0, 0, 0);
        if (row0 + row < M) {
            int node = idxp[row0 + row];
            pk = ((const uint4*)(h1 + (size_t)node * 128))[c];
        }
        *(uint4*)(hS + row * 136 + c * 8) = pk;
    }
    __syncthreads();

    const int wave = t >> 6, lane = t & 63;
    const int quad = lane >> 4, l16 = lane & 15;
    const int wr = (wave & 1) * 64, wcl = (wave >> 1) * 64;
    const int sr = t >> 1, scc = (t & 1) * 16;
    uint4 pv0, pv1;
    {
        const uint4* bp = (const uint4*)(qkvw1 + (size_t)(ch * 128 + sr) * 128 + scc);
        pv0 = bp[0]; pv1 = bp[1];
    }
    f32x4 acc[4][4];
    #pragma unroll
    for (int i = 0; i < 4; ++i)
        #pragma unroll
        for (int j = 0; j < 4; ++j)
            acc[i][j] = (f32x4){0.f, 0.f, 0.f, 0.f};
    for (int it = 0; it < 4; ++it) {
        __syncthreads();
        *(uint4*)(Bs + sr * 40 + scc)     = pv0;
        *(uint4*)(Bs + sr * 40 + scc + 8) = pv1;
        __syncthreads();
        if (it + 1 < 4) {
            const uint4* bp = (const uint4*)(qkvw1 + (size_t)(ch * 128 + sr) * 128 + (it + 1) * 32 + scc);
            pv0 = bp[0]; pv1 = bp[1];
        }
        bf16x8 af[4], bfr[4];
        #pragma unroll
        for (int f = 0; f < 4; ++f) {
            af[f]  = *(const bf16x8*)(hS + (wr + f * 16 + l16) * 136 + it * 32 + quad * 8);
            bfr[f] = *(const bf16x8*)(Bs + (wcl + f * 16 + l16) * 40 + quad * 8);
        }
        #pragma unroll
        for (int fr = 0; fr < 4; ++fr)
            #pragma unroll
            for (int fc = 0; fc < 4; ++fc)
                acc[fr][fc] = __builtin_amdgcn_mfma_f32_16x16x32_bf16(
                    af[fr], bfr[fc], acc[fr][fc], 0, 0, 0);
    }
    float b4[4];
    #pragma unroll
    for (int fc = 0; fc < 4; ++fc)
        b4[fc] = fbias1[ch * 128 + wcl + fc * 16 + l16];
    #pragma unroll
    for (int fr = 0; fr < 4; ++fr)
        #pragma unroll
        for (int reg = 0; reg < 4; ++reg) {
            int row = row0 + wr + fr * 16 + quad * 4 + reg;
            if (row >= M) continue;
            #pragma unroll
            for (int fc = 0; fc < 4; ++fc) {
                int col = ch * 128 + wcl + fc * 16 + l16;
                q1[(size_t)row * 512 + col] = f2bf(acc[fr][fc][reg] + b4[fc]);
            }
        }
}

// ============ layer-1 MLP (compact rows, block-diagonal stage 1): out = gate*(...) + (1-g)*h1[idx] ====
__global__ __launch_bounds__(256) void mlp1_kernel(
    const unsigned short* __restrict__ A, const unsigned short* __restrict__ W3c,
    const unsigned short* __restrict__ AWt, const float* __restrict__ a_bias,
    const float* __restrict__ skipv, const unsigned short* __restrict__ hres,
    const int* __restrict__ rowmap, float* __restrict__ out, int M)
{
    __shared__ unsigned short Bs[128 * 40];
    __shared__ unsigned short msgS[128 * 136];
    const int t = threadIdx.x;
    const int wave = t >> 6, lane = t & 63;
    const int quad = lane >> 4, l16 = lane & 15;
    const int row0 = blockIdx.x * 128;
    const int wr = (wave & 1) * 64, wcl = (wave >> 1) * 64;
    const int sr = t >> 1, scc = (t & 1) * 16;
    const int scc2 = (t & 1) * 64;
    const int grow = row0 + sr;
    const bool rvalid = grow < M;
    const int h2b = wcl >> 5;

    f32x4 acc[4][4];
    #pragma unroll
    for (int i = 0; i < 4; ++i)
        #pragma unroll
        for (int j = 0; j < 4; ++j)
            acc[i][j] = (f32x4){0.f, 0.f, 0.f, 0.f};

    uint4 av[8];
    #pragma unroll
    for (int j = 0; j < 8; ++j) av[j] = make_uint4(0, 0, 0, 0);
    if (rvalid) {
        const uint4* ap = (const uint4*)(A + (size_t)grow * 512 + scc2);
        #pragma unroll
        for (int j = 0; j < 8; ++j) av[j] = ap[j];
    }
    uint4 bw0, bw1;
    {
        const uint4* bp = (const uint4*)(W3c + sr * 32 + scc);
        bw0 = bp[0]; bw1 = bp[1];
    }
    for (int it = 0; it < 4; ++it) {
        __syncthreads();
        #pragma unroll
        for (int j = 0; j < 8; ++j)
            *(uint4*)(msgS + sr * 136 + scc2 + j * 8) = av[j];
        *(uint4*)(Bs + sr * 40 + scc)     = bw0;
        *(uint4*)(Bs + sr * 40 + scc + 8) = bw1;
        __syncthreads();
        if (it + 1 < 4) {
            if (rvalid) {
                const uint4* ap = (const uint4*)(A + (size_t)grow * 512 + (it + 1) * 128 + scc2);
                #pragma unroll
                for (int j = 0; j < 8; ++j) av[j] = ap[j];
            }
            const uint4* bp = (const uint4*)(W3c + (it + 1) * 4096 + sr * 32 + scc);
            bw0 = bp[0]; bw1 = bp[1];
        }
        bf16x8 af2[2][4], bfr[4];
        #pragma unroll
        for (int g = 0; g < 2; ++g)
            #pragma unroll
            for (int f = 0; f < 4; ++f)
                af2[g][f] = *(const bf16x8*)(msgS + (wr + f * 16 + l16) * 136 + (h2b + g) * 32 + quad * 8);
        #pragma unroll
        for (int f = 0; f < 4; ++f)
            bfr[f] = *(const bf16x8*)(Bs + (wcl + f * 16 + l16) * 40 + quad * 8);
        #pragma unroll
        for (int fr = 0; fr < 4; ++fr)
            #pragma unroll
            for (int fc = 0; fc < 4; ++fc)
                acc[fr][fc] = __builtin_amdgcn_mfma_f32_16x16x32_bf16(
                    af2[fc >> 1][fr], bfr[fc], acc[fr][fc], 0, 0, 0);
    }
    __syncthreads();      // stage-1 msgS reads complete before gelu overwrite

    #pragma unroll
    for (int fr = 0; fr < 4; ++fr)
        #pragma unroll
        for (int reg = 0; reg < 4; ++reg) {
            int rl = wr + fr * 16 + quad * 4 + reg;
            #pragma unroll
            for (int fc = 0; fc < 4; ++fc) {
                int col = wcl + fc * 16 + l16;
                float v = acc[fr][fc][reg];
                float gl = 0.5f * v * (1.f + erff(v * 0.70710678118654752f));
                msgS[rl * 136 + col] = f2bf(gl);
            }
        }

    f32x4 acc2[4][4];
    #pragma unroll
    for (int i = 0; i < 4; ++i)
        #pragma unroll
        for (int j = 0; j < 4; ++j)
            acc2[i][j] = (f32x4){0.f, 0.f, 0.f, 0.f};
    uint4 pv0, pv1;
    {
        const uint4* bp = (const uint4*)(AWt + (size_t)sr * 128 + scc);
        pv0 = bp[0]; pv1 = bp[1];
    }
    for (int it = 0; it < 4; ++it) {
        __syncthreads();
        *(uint4*)(Bs + sr * 40 + scc)     = pv0;
        *(uint4*)(Bs + sr * 40 + scc + 8) = pv1;
        __syncthreads();
        if (it + 1 < 4) {
            const uint4* bp = (const uint4*)(AWt + (size_t)sr * 128 + (it + 1) * 32 + scc);
            pv0 = bp[0]; pv1 = bp[1];
        }
        bf16x8 af[4], bfr[4];
        #pragma unroll
        for (int f = 0; f < 4; ++f) {
            af[f]  = *(const bf16x8*)(msgS + (wr + f * 16 + l16) * 136 + it * 32 + quad * 8);
            bfr[f] = *(const bf16x8*)(Bs + (wcl + f * 16 + l16) * 40 + quad * 8);
        }
        #pragma unroll
        for (int fr = 0; fr < 4; ++fr)
            #pragma unroll
            for (int fc = 0; fc < 4; ++fc)
                acc2[fr][fc] = __builtin_amdgcn_mfma_f32_16x16x32_bf16(
                    af[fr], bfr[fc], acc2[fr][fc], 0, 0, 0);
    }

    const float gate = 1.f / (1.f + __expf(-skipv[0]));
    #pragma unroll
    for (int fr = 0; fr < 4; ++fr)
        #pragma unroll
        for (int reg = 0; reg < 4; ++reg) {
            int row = row0 + wr + fr * 16 + quad * 4 + reg;
            if (row >= M) continue;
            int hrow = rowmap[row];
            #pragma unroll
            for (int fc = 0; fc < 4; ++fc) {
                int col = wcl + fc * 16 + l16;
                float val = acc2[fr][fc][reg] + a_bias[col];
                float nv = gate * val + (1.f - gate) * bf2f((unsigned int)hres[(size_t)hrow * 128 + col]);
                out[(size_t)row * 128 + col] = nv;
            }
        }
}

extern "C" void kernel_launch(void* const* d_in, const int* in_sizes, int n_in,
                              void* d_out, int out_size, void* d_ws, size_t ws_size,
                              hipStream_t stream)
{
    const float* x      = (const float*)d_in[0];
    const float* proj_w = (const float*)d_in[1];
    const float* proj_b = (const float*)d_in[2];
    const float* bn_g   = (const float*)d_in[3];
    const float* bn_b   = (const float*)d_in[4];
    const float* q_w    = (const float*)d_in[5];
    const float* q_b    = (const float*)d_in[6];
    const float* k_w    = (const float*)d_in[7];
    const float* k_b    = (const float*)d_in[8];
    const float* v_w    = (const float*)d_in[9];
    const float* v_b    = (const float*)d_in[10];
    const float* a_w    = (const float*)d_in[11];
    const float* a_b    = (const float*)d_in[12];
    const float* skip   = (const float*)d_in[13];
    const float* a_rel  = (const float*)d_in[14];
    const float* m_rel  = (const float*)d_in[15];
    const float* p_rel  = (const float*)d_in[16];
    const int* edge_index = (const int*)d_in[17];
    const int* edge_type  = (const int*)d_in[18];
    const int* idx        = (const int*)d_in[19];
    float* out = (float*)d_out;

    const int N = NN, E = EE;
    float* ws = (float*)d_ws;
    size_t o = 0;
    float* stats  = ws + o;  o += 256;
    float* fbias  = ws + o;  o += 2 * 768;
    int* cnt  = (int*)(ws + o); o += NT4;
    int* off4 = (int*)(ws + o); o += NT4 + 1;
    int* fill = (int*)(ws + o); o += NT4;
    int* bsum = (int*)(ws + o); o += 1024;
    int* pack = (int*)(ws + o); o += E;
    unsigned short* x_bf   = (unsigned short*)(ws + o); o += (size_t)N * 64;  // scratch; reused by q1
    unsigned short* h_bf   = (unsigned short*)(ws + o); o += (size_t)N * 64;
    unsigned short* hn_bf  = (unsigned short*)(ws + o); o += (size_t)N * 64;
    unsigned short* h1_bf  = (unsigned short*)(ws + o); o += (size_t)N * 64;
    unsigned short* qkv_bf = (unsigned short*)(ws + o); o += (size_t)N * 384;
    unsigned short* agg_bf = (unsigned short*)(ws + o); o += (size_t)N * 256;
    unsigned short* wt_pa  = (unsigned short*)(ws + o); o += 3 * 16384 / 2;
    unsigned short* qkvw   = (unsigned short*)(ws + o); o += 2 * 98304 / 2;
    unsigned short* msg_wt = (unsigned short*)(ws + o); o += 2 * 65536 / 2;   // uses first 2*16384 now

    // idx-membership mask (50000 bytes) reuses cnt[0:12500) — dead after scan_block.
    unsigned char* mask = (unsigned char*)cnt;
    // q1 compact buffer [MOUT][512] reuses x_bf region.
    unsigned short* q1 = x_bf;   // 10000*512 shorts = 5.12M <= N*128 shorts

    const int NB4 = (NT4 + 255) / 256;          // 782
    const int g = (N + 127) / 128;              // 391

    // 1) prep: weights (compact msg), zero cnt/stats
    prep_kernel<<<1088 + NB4, 256, 0, stream>>>(
        proj_w, a_w, q_w, q_b, a_rel, k_w, k_b, v_w, v_b, m_rel, p_rel,
        wt_pa, qkvw, fbias, msg_wt, cnt, stats);

    // 2-5) CSR build; scan_add zeroes mask region (cnt dead), scatter sets mask
    hist_kernel<<<(E + 255) / 256, 256, 0, stream>>>(edge_index, edge_type, cnt, E);
    scan_block_kernel<<<NB4, 256, 0, stream>>>(cnt, off4, bsum, NT4);
    scan_add_kernel<<<NB4, 256, 0, stream>>>(off4, bsum, fill, cnt, NT4, E);
    scatter_kernel<<<(E + 255) / 256, 256, 0, stream>>>(edge_index, edge_type, fill,
                                                        pack, idx, mask, MOUT, E);

    // 6) proj GEMM + BN stats (A = x f32, cast in-register)
    projstats_kernel<<<g, 256, 0, stream>>>(x, wt_pa, proj_b, h_bf, stats, N);

    // 7) BN apply + qkv0 — chunk-split: 3 blocks/row-tile, 2 chunks each
    {
        dim3 grid(g, 3);
        bnqkv_kernel<<<grid, 256, 0, stream>>>(h_bf, stats, bn_g, bn_b, qkvw, fbias,
                                               hn_bf, qkv_bf, N);
    }

    // 8) attention layer 0 (all nodes; pair-processing, 16B kv chunks)
    agg_fused_kernel<<<(N + 3) / 4, 256, 0, stream>>>(qkv_bf, qkv_bf, 768,
                                                      off4, pack, nullptr, agg_bf, N);

    // 9) MLP0 (block-diag stage 1) + residual + qkv1 KV for all nodes
    mlpqkv_kernel<<<g, 256, 0, stream>>>(agg_bf, msg_wt, wt_pa + 16384, a_b, skip,
                                         hn_bf, qkvw + 98304, fbias + 768,
                                         mask, h1_bf, qkv_bf, N);

    // 9.5) compact layer-1 q — chunk-split: 4 blocks/row-tile, 1 chunk each
    {
        dim3 gq((MOUT + 127) / 128, 4);
        q1_kernel<<<gq, 256, 0, stream>>>(h1_bf, idx, qkvw + 98304, fbias + 768, q1, MOUT);
    }

    // 10) attention layer 1 (idx rows; q from compact q1, kv gathered from qkv)
    agg_fused_kernel<<<(MOUT + 3) / 4, 256, 0, stream>>>(qkv_bf, q1, 512,
                                                         off4, pack, idx, agg_bf, MOUT);

    // 11) MLP1 (block-diag stage 1) + residual -> out
    mlp1_kernel<<<(MOUT + 127) / 128, 256, 0, stream>>>(agg_bf, msg_wt + 16384,
                                                        wt_pa + 2 * 16384, a_b + 128,
                                                        skip + 1, h1_bf, idx, out, MOUT);
}

// Round 12
// 402.749 us; speedup vs baseline: 1.1552x; 1.0610x over previous
//
#include <hip/hip_runtime.h>
#include <math.h>

#define NN 50000
#define EE 600000
#define MOUT 10000
#define DEGCAP 384
#define NT4 (NN * 4)

typedef short bf16x8 __attribute__((ext_vector_type(8)));
typedef float f32x4 __attribute__((ext_vector_type(4)));

__device__ __forceinline__ unsigned short f2bf(float x) {
    unsigned int u = __float_as_uint(x);
    u = (u + 0x7FFFu + ((u >> 16) & 1u)) >> 16;
    return (unsigned short)u;
}
__device__ __forceinline__ float bf2f(unsigned int b) {
    return __uint_as_float(b << 16);
}
__device__ __forceinline__ uint4 pack8bf(float4 a, float4 b) {
    uint4 r;
    r.x = (unsigned int)f2bf(a.x) | ((unsigned int)f2bf(a.y) << 16);
    r.y = (unsigned int)f2bf(a.z) | ((unsigned int)f2bf(a.w) << 16);
    r.z = (unsigned int)f2bf(b.x) | ((unsigned int)f2bf(b.y) << 16);
    r.w = (unsigned int)f2bf(b.z) | ((unsigned int)f2bf(b.w) << 16);
    return r;
}

// ============ merged weight prep + CSR/stats zeroing ============
// qkv weight rows 512..767 PERMUTED into 16B chunks (k[4t..4t+3], v[4t..4t+3]);
// qrel rows pre-scaled by p_rel/sqrt(32).
// msg weight stored COMPACT block-diagonal: msg_wt2[(l*4+r)*4096 + n*32 + d]
//   = m_rel[l][r][h=n>>5][d][e=n&31].
__global__ __launch_bounds__(256) void prep_kernel(
    const float* __restrict__ proj_w, const float* __restrict__ a_w,
    const float* __restrict__ q_w, const float* __restrict__ q_b,
    const float* __restrict__ a_rel,
    const float* __restrict__ k_w, const float* __restrict__ k_b,
    const float* __restrict__ v_w, const float* __restrict__ v_b,
    const float* __restrict__ m_rel, const float* __restrict__ p_rel,
    unsigned short* __restrict__ wt_pa, unsigned short* __restrict__ qkvw,
    float* __restrict__ fbias, unsigned short* __restrict__ msg_wt,
    int* __restrict__ cnt, float* __restrict__ stats)
{
    const int b = blockIdx.x, t = threadIdx.x;
    if (b < 192) {                       // proj^T, a_w0^T, a_w1^T
        int wi = b >> 6;
        int flat = (b & 63) * 256 + t;
        int n = flat >> 7, c = flat & 127;
        const float* src = (wi == 0) ? proj_w : (wi == 1) ? a_w : a_w + 16384;
        wt_pa[(size_t)wi * 16384 + n * 128 + c] = f2bf(src[c * 128 + n]);
    } else if (b < 960) {                // fused qkv weight [768][128] per layer
        int q = b - 192;
        int l = q >= 384 ? 1 : 0;
        int flat = (q - l * 384) * 256 + t;
        int nrow = flat >> 7, c = flat & 127;
        unsigned short* wt = qkvw + (size_t)l * 98304;
        float* fb = fbias + l * 768;
        if (nrow < 512) {
            int r = nrow >> 7, hh = (nrow >> 5) & 3, d = nrow & 31;
            float prl = p_rel[l * 16 + r * 4 + hh] * 0.17677669529663687f;
            const float* qwc = q_w + (size_t)l * 16384 + c * 128 + hh * 32;
            const float* ar  = a_rel + (size_t)(l * 4 + r) * 4096 + hh * 1024 + d * 32;
            float s = 0.f;
            #pragma unroll 8
            for (int e = 0; e < 32; ++e) s += qwc[e] * ar[e];
            wt[(size_t)nrow * 128 + c] = f2bf(s * prl);
            if (c == 0) {
                const float* qb = q_b + l * 128 + hh * 32;
                float bb = 0.f;
                #pragma unroll 8
                for (int e = 0; e < 32; ++e) bb += qb[e] * ar[e];
                fb[nrow] = bb * prl;
            }
        } else {                         // k/v 16B-chunk rows: t-th chunk = k[4t..4t+3], v[4t..4t+3]
            int j = nrow - 512;
            int tt = j >> 3, s = j & 7;
            int col = 4 * tt + (s & 3);
            const float* w  = (s < 4) ? k_w : v_w;
            const float* bb = (s < 4) ? k_b : v_b;
            wt[(size_t)nrow * 128 + c] = f2bf(w[(size_t)l * 16384 + c * 128 + col]);
            if (c == 0) fb[nrow] = bb[l * 128 + col];
        }
    } else if (b < 1088) {               // compact msg weight: 2 layers x 4 rel x [128 n][32 d]
        int q = b - 960;
        int l = q >= 64 ? 1 : 0;
        int flat = (q - l * 64) * 256 + t;     // 0 .. 16383
        int r = flat >> 12, rem = flat & 4095;
        int n = rem >> 5, d = rem & 31;
        float val = m_rel[(size_t)(l * 4 + r) * 4096 + (n >> 5) * 1024 + d * 32 + (n & 31)];
        msg_wt[(size_t)l * 16384 + r * 4096 + n * 32 + d] = f2bf(val);
    } else {                             // zero cnt + stats
        int i = (b - 1088) * 256 + t;
        if (i < NT4) cnt[i] = 0;
        if (i < 256) stats[i] = 0.f;
    }
}

// ============ CSR build ============
__global__ __launch_bounds__(256) void hist_kernel(const int* __restrict__ ei,
    const int* __restrict__ et, int* __restrict__ cnt, int E)
{
    int e = blockIdx.x * 256 + threadIdx.x;
    if (e < E) atomicAdd(&cnt[ei[E + e] * 4 + et[e]], 1);
}

__global__ __launch_bounds__(256) void scan_block_kernel(const int* __restrict__ cnt,
    int* __restrict__ excl, int* __restrict__ bsum, int n)
{
    __shared__ int tmp[256];
    int i = blockIdx.x * 256 + threadIdx.x;
    int v = (i < n) ? cnt[i] : 0;
    tmp[threadIdx.x] = v;
    __syncthreads();
    for (int ofs = 1; ofs < 256; ofs <<= 1) {
        int t = (threadIdx.x >= ofs) ? tmp[threadIdx.x - ofs] : 0;
        __syncthreads();
        tmp[threadIdx.x] += t;
        __syncthreads();
    }
    if (i < n) excl[i] = tmp[threadIdx.x] - v;
    if (threadIdx.x == 255) bsum[blockIdx.x] = tmp[255];
}

// per-block prefix over bsum; ALSO zeroes the idx-mask region (reuses dead cnt[0:12500))
__global__ __launch_bounds__(256) void scan_add_kernel(int* __restrict__ excl,
    const int* __restrict__ bsum, int* __restrict__ fill,
    int* __restrict__ maskz, int n, int total)
{
    __shared__ int red[256];
    const int b = blockIdx.x;
    int partial = 0;
    for (int j = threadIdx.x; j < b; j += 256) partial += bsum[j];
    red[threadIdx.x] = partial;
    __syncthreads();
    for (int ofs = 128; ofs > 0; ofs >>= 1) {
        if (threadIdx.x < ofs) red[threadIdx.x] += red[threadIdx.x + ofs];
        __syncthreads();
    }
    int prefix = red[0];
    int i = b * 256 + threadIdx.x;
    if (i < n) {
        int o = excl[i] + prefix;
        excl[i] = o;
        fill[i] = o;
    }
    if (i < 12500) maskz[i] = 0;         // cnt region is dead after scan_block
    if (b == 0 && threadIdx.x == 0) excl[n] = total;
}

// scatter + idx-membership mask set (mask lives in old cnt region)
__global__ __launch_bounds__(256) void scatter_kernel(const int* __restrict__ ei,
    const int* __restrict__ et, int* __restrict__ fill, int* __restrict__ pack,
    const int* __restrict__ idxp, unsigned char* __restrict__ mask, int Mo, int E)
{
    int e = blockIdx.x * 256 + threadIdx.x;
    if (e >= E) return;
    int seg = ei[E + e] * 4 + et[e];
    int p = atomicAdd(&fill[seg], 1);
    pack[p] = ei[e];
    if (e < Mo) mask[idxp[e]] = 1;
}

// ============ proj GEMM + BN-stats epilogue, A loaded as f32 and cast in-register ============
__global__ __launch_bounds__(256) void projstats_kernel(
    const float* __restrict__ X, const unsigned short* __restrict__ Wt,
    const float* __restrict__ bias, unsigned short* __restrict__ Cb,
    float* __restrict__ stats, int M)
{
    __shared__ unsigned short As[128 * 40];
    __shared__ unsigned short Bs[128 * 40];
    const int t = threadIdx.x;
    const int wave = t >> 6, lane = t & 63;
    const int quad = lane >> 4, l16 = lane & 15;
    const int row0 = blockIdx.x * 128;
    const int wr = (wave & 1) * 64, wc = (wave >> 1) * 64;
    const int sr = t >> 1, sc = (t & 1) * 16;
    const int grow = row0 + sr;

    f32x4 acc[4][4];
    #pragma unroll
    for (int i = 0; i < 4; ++i)
        #pragma unroll
        for (int j = 0; j < 4; ++j)
            acc[i][j] = (f32x4){0.f, 0.f, 0.f, 0.f};

    uint4 av0 = make_uint4(0,0,0,0), av1 = av0, bv0, bv1;
    if (grow < M) {
        const float4* ap = (const float4*)(X + (size_t)grow * 128 + sc);
        av0 = pack8bf(ap[0], ap[1]);
        av1 = pack8bf(ap[2], ap[3]);
    }
    {
        const uint4* bp = (const uint4*)(Wt + (size_t)sr * 128 + sc);
        bv0 = bp[0]; bv1 = bp[1];
    }
    for (int it = 0; it < 4; ++it) {
        __syncthreads();
        *(uint4*)(As + sr * 40 + sc)     = av0;
        *(uint4*)(As + sr * 40 + sc + 8) = av1;
        *(uint4*)(Bs + sr * 40 + sc)     = bv0;
        *(uint4*)(Bs + sr * 40 + sc + 8) = bv1;
        __syncthreads();
        if (it + 1 < 4) {
            int kb = (it + 1) * 32;
            if (grow < M) {
                const float4* ap = (const float4*)(X + (size_t)grow * 128 + kb + sc);
                av0 = pack8bf(ap[0], ap[1]);
                av1 = pack8bf(ap[2], ap[3]);
            }
            const uint4* bp = (const uint4*)(Wt + (size_t)sr * 128 + kb + sc);
            bv0 = bp[0]; bv1 = bp[1];
        }
        bf16x8 af[4], bfr[4];
        #pragma unroll
        for (int f = 0; f < 4; ++f) {
            af[f]  = *(const bf16x8*)(As + (wr + f * 16 + l16) * 40 + quad * 8);
            bfr[f] = *(const bf16x8*)(Bs + (wc + f * 16 + l16) * 40 + quad * 8);
        }
        #pragma unroll
        for (int fr = 0; fr < 4; ++fr)
            #pragma unroll
            for (int fc = 0; fc < 4; ++fc)
                acc[fr][fc] = __builtin_amdgcn_mfma_f32_16x16x32_bf16(
                    af[fr], bfr[fc], acc[fr][fc], 0, 0, 0);
    }

    #pragma unroll
    for (int fc = 0; fc < 4; ++fc) {
        const int col = wc + fc * 16 + l16;
        const float bv = bias[col];
        float s = 0.f, s2 = 0.f;
        #pragma unroll
        for (int fr = 0; fr < 4; ++fr)
            #pragma unroll
            for (int reg = 0; reg < 4; ++reg) {
                int row = row0 + wr + fr * 16 + quad * 4 + reg;
                float val = acc[fr][fc][reg] + bv;
                if (row < M) {
                    Cb[(size_t)row * 128 + col] = f2bf(val);
                    s += val; s2 += val * val;
                }
            }
        s  += __shfl_xor(s, 16);  s  += __shfl_xor(s, 32);
        s2 += __shfl_xor(s2, 16); s2 += __shfl_xor(s2, 32);
        if (quad == 0) {
            atomicAdd(&stats[col], s);
            atomicAdd(&stats[128 + col], s2);
        }
    }
}

// ============ BN-apply + qkv0 GEMM, CHUNK-SPLIT: gridDim.y=3, 2 col-chunks per block ============
__global__ __launch_bounds__(256) void bnqkv_kernel(
    const unsigned short* __restrict__ hb, const float* __restrict__ stats,
    const float* __restrict__ gamma, const float* __restrict__ beta,
    const unsigned short* __restrict__ qkvw, const float* __restrict__ fbias,
    unsigned short* __restrict__ hn, unsigned short* __restrict__ qkv, int M)
{
    __shared__ unsigned short hS[128 * 136];
    __shared__ unsigned short Bs[128 * 40];
    __shared__ float mulS[128], addS[128];
    const int t = threadIdx.x;
    const int row0 = blockIdx.x * 128;
    const int ch0 = blockIdx.y * 2;
    if (t < 128) {
        float invN = 1.f / 50000.f;
        float mu = stats[t] * invN;
        float var = stats[128 + t] * invN - mu * mu;
        float ml = rsqrtf(var + 1e-5f) * gamma[t];
        mulS[t] = ml;
        addS[t] = beta[t] - mu * ml;
    }
    __syncthreads();
    #pragma unroll
    for (int u = 0; u < 8; ++u) {
        int li = t + u * 256;                 // uint4 index; 16 per row
        int row = li >> 4, c0 = (li & 15) * 8;
        uint4 pk = make_uint4(0, 0, 0, 0);
        if (row0 + row < M)
            pk = ((const uint4*)(hb + (size_t)(row0 + row) * 128))[li & 15];
        unsigned int w[4] = {pk.x, pk.y, pk.z, pk.w};
        uint4 o;
        unsigned int ov[4];
        #pragma unroll
        for (int g = 0; g < 4; ++g) {
            int c = c0 + g * 2;
            float a0 = bf2f(w[g] & 0xFFFFu) * mulS[c]     + addS[c];
            float a1 = bf2f(w[g] >> 16)     * mulS[c + 1] + addS[c + 1];
            ov[g] = (unsigned int)f2bf(a0) | ((unsigned int)f2bf(a1) << 16);
        }
        o.x = ov[0]; o.y = ov[1]; o.z = ov[2]; o.w = ov[3];
        *(uint4*)(hS + row * 136 + c0) = o;
        if (blockIdx.y == 0 && row0 + row < M)
            ((uint4*)(hn + (size_t)(row0 + row) * 128))[li & 15] = o;
    }
    __syncthreads();

    const int wave = t >> 6, lane = t & 63;
    const int quad = lane >> 4, l16 = lane & 15;
    const int wr = (wave & 1) * 64, wcl = (wave >> 1) * 64;
    const int sr = t >> 1, scc = (t & 1) * 16;

    // weight prefetch registers for (ch=ch0, it=0)
    uint4 pv0, pv1;
    {
        const uint4* bp = (const uint4*)(qkvw + (size_t)(ch0 * 128 + sr) * 128 + scc);
        pv0 = bp[0]; pv1 = bp[1];
    }
    for (int ch = ch0; ch < ch0 + 2; ++ch) {
        f32x4 acc[4][4];
        #pragma unroll
        for (int i = 0; i < 4; ++i)
            #pragma unroll
            for (int j = 0; j < 4; ++j)
                acc[i][j] = (f32x4){0.f, 0.f, 0.f, 0.f};
        for (int it = 0; it < 4; ++it) {
            __syncthreads();
            *(uint4*)(Bs + sr * 40 + scc)     = pv0;
            *(uint4*)(Bs + sr * 40 + scc + 8) = pv1;
            __syncthreads();
            int nit = it + 1, nch = ch;
            if (nit == 4) { nit = 0; ++nch; }
            if (nch < ch0 + 2) {
                const uint4* bp = (const uint4*)(qkvw + (size_t)(nch * 128 + sr) * 128 + nit * 32 + scc);
                pv0 = bp[0]; pv1 = bp[1];
            }
            bf16x8 af[4], bfr[4];
            #pragma unroll
            for (int f = 0; f < 4; ++f) {
                af[f]  = *(const bf16x8*)(hS + (wr + f * 16 + l16) * 136 + it * 32 + quad * 8);
                bfr[f] = *(const bf16x8*)(Bs + (wcl + f * 16 + l16) * 40 + quad * 8);
            }
            #pragma unroll
            for (int fr = 0; fr < 4; ++fr)
                #pragma unroll
                for (int fc = 0; fc < 4; ++fc)
                    acc[fr][fc] = __builtin_amdgcn_mfma_f32_16x16x32_bf16(
                        af[fr], bfr[fc], acc[fr][fc], 0, 0, 0);
        }
        float b4[4];
        #pragma unroll
        for (int fc = 0; fc < 4; ++fc)
            b4[fc] = fbias[ch * 128 + wcl + fc * 16 + l16];
        #pragma unroll
        for (int fr = 0; fr < 4; ++fr)
            #pragma unroll
            for (int reg = 0; reg < 4; ++reg) {
                int row = row0 + wr + fr * 16 + quad * 4 + reg;
                if (row >= M) continue;
                #pragma unroll
                for (int fc = 0; fc < 4; ++fc) {
                    int col = ch * 128 + wcl + fc * 16 + l16;
                    qkv[(size_t)row * 768 + col] = f2bf(acc[fr][fc][reg] + b4[fc]);
                }
            }
    }
}

// ============ fused attention: per-node wave, PAIR processing (2 edges across wave halves) ====
__global__ __launch_bounds__(256) void agg_fused_kernel(
    const unsigned short* __restrict__ qkv,
    const unsigned short* __restrict__ qbuf, int qpitch,
    const int* __restrict__ off4, const int* __restrict__ pack,
    const int* __restrict__ rowmap, unsigned short* __restrict__ aggb, int count)
{
    __shared__ int spack[4][DEGCAP];
    const int wv = threadIdx.x >> 6;
    const int lane = threadIdx.x & 63;
    const int l32 = lane & 31;
    const int hi = lane >> 5;
    const int unit = blockIdx.x * 4 + wv;
    if (unit >= count) return;                 // no __syncthreads in this kernel
    const int node = rowmap ? __builtin_amdgcn_readfirstlane(rowmap[unit]) : unit;

    // q dims [4*l32 .. 4*l32+3] per run (both halves need the same dims)
    const uint2* qrow = (const uint2*)(qbuf + (size_t)unit * qpitch);
    uint2 quv[4];
    #pragma unroll
    for (int r = 0; r < 4; ++r) quv[r] = qrow[r * 32 + l32];

    int off_r[5];
    #pragma unroll
    for (int i = 0; i < 5; ++i)
        off_r[i] = __builtin_amdgcn_readfirstlane(off4[node * 4 + i]);
    const int beg = off_r[0];
    const int deg = off_r[4] - beg;
    const bool cached = deg <= DEGCAP;

    if (cached) {
        for (int i = lane; i < deg; i += 64) spack[wv][i] = pack[beg + i];
        asm volatile("s_waitcnt vmcnt(0) lgkmcnt(0)" ::: "memory");
    }

    uint2 outw[4];
    #pragma unroll
    for (int r = 0; r < 4; ++r) {
        float q0 = bf2f(quv[r].x & 0xFFFFu), q1 = bf2f(quv[r].x >> 16);
        float q2 = bf2f(quv[r].y & 0xFFFFu), q3 = bf2f(quv[r].y >> 16);
        float den = 0.f, a0 = 0.f, a1 = 0.f, a2 = 0.f, a3 = 0.f;

        if (cached) {
            const int rb = off_r[r] - beg, re = off_r[r + 1] - beg;
            for (int i = rb; i < re; i += 4) {
                int i0 = i + hi;      if (i0 >= re) i0 = re - 1;
                int i1 = i + 2 + hi;  if (i1 >= re) i1 = re - 1;
                int s0 = spack[wv][i0], s1 = spack[wv][i1];
                uint4 kv0 = *(const uint4*)(qkv + (size_t)s0 * 768 + 512 + l32 * 8);
                uint4 kv1 = *(const uint4*)(qkv + (size_t)s1 * 768 + 512 + l32 * 8);
                {
                    float p = q0 * bf2f(kv0.x & 0xFFFFu) + q1 * bf2f(kv0.x >> 16)
                            + q2 * bf2f(kv0.y & 0xFFFFu) + q3 * bf2f(kv0.y >> 16);
                    p += __shfl_xor(p, 1); p += __shfl_xor(p, 2); p += __shfl_xor(p, 4);
                    float e = __expf(fminf(fmaxf(p, -80.f), 80.f));
                    if (i + hi >= re) e = 0.f;
                    den += e;
                    a0 += e * bf2f(kv0.z & 0xFFFFu); a1 += e * bf2f(kv0.z >> 16);
                    a2 += e * bf2f(kv0.w & 0xFFFFu); a3 += e * bf2f(kv0.w >> 16);
                }
                {
                    float p = q0 * bf2f(kv1.x & 0xFFFFu) + q1 * bf2f(kv1.x >> 16)
                            + q2 * bf2f(kv1.y & 0xFFFFu) + q3 * bf2f(kv1.y >> 16);
                    p += __shfl_xor(p, 1); p += __shfl_xor(p, 2); p += __shfl_xor(p, 4);
                    float e = __expf(fminf(fmaxf(p, -80.f), 80.f));
                    if (i + 2 + hi >= re) e = 0.f;
                    den += e;
                    a0 += e * bf2f(kv1.z & 0xFFFFu); a1 += e * bf2f(kv1.z >> 16);
                    a2 += e * bf2f(kv1.w & 0xFFFFu); a3 += e * bf2f(kv1.w >> 16);
                }
            }
        } else {   // giant-degree fallback: pair walk straight from pack
            const int pe_end = off_r[r + 1];
            for (int pp = off_r[r]; pp < pe_end; pp += 2) {
                int pe = pp + hi; if (pe >= pe_end) pe = pe_end - 1;
                int src = pack[pe];
                uint4 kv = *(const uint4*)(qkv + (size_t)src * 768 + 512 + l32 * 8);
                float p = q0 * bf2f(kv.x & 0xFFFFu) + q1 * bf2f(kv.x >> 16)
                        + q2 * bf2f(kv.y & 0xFFFFu) + q3 * bf2f(kv.y >> 16);
                p += __shfl_xor(p, 1); p += __shfl_xor(p, 2); p += __shfl_xor(p, 4);
                float e = __expf(fminf(fmaxf(p, -80.f), 80.f));
                if (pp + hi >= pe_end) e = 0.f;
                den += e;
                a0 += e * bf2f(kv.z & 0xFFFFu); a1 += e * bf2f(kv.z >> 16);
                a2 += e * bf2f(kv.w & 0xFFFFu); a3 += e * bf2f(kv.w >> 16);
            }
        }
        // merge the two halves (lane l and l+32 hold the same dims, different edges)
        den += __shfl_xor(den, 32);
        a0  += __shfl_xor(a0, 32);
        a1  += __shfl_xor(a1, 32);
        a2  += __shfl_xor(a2, 32);
        a3  += __shfl_xor(a3, 32);
        float inv = den > 0.f ? 1.f / den : 0.f;
        outw[r].x = (unsigned int)f2bf(a0 * inv) | ((unsigned int)f2bf(a1 * inv) << 16);
        outw[r].y = (unsigned int)f2bf(a2 * inv) | ((unsigned int)f2bf(a3 * inv) << 16);
    }
    if (hi == 0) {
        uint2* op = (uint2*)(aggb + (size_t)unit * 512);
        #pragma unroll
        for (int r = 0; r < 4; ++r) op[r * 32 + l32] = outw[r];
    }
}

// ============ layer-0 MLP + qkv1-kv: 64-ROW TILES, 4 waves x (64 rows x 32 cols) ============
// h1 = gate*(gelu(agg@W3)@AW + b) + (1-g)*hn; qkv1 kv cols for ALL nodes;
// h1 stored only at idx rows (mask). Stage 1 block-diagonal: each wave's 32-col
// block is exactly one head -> single A-fragment group.
__global__ __launch_bounds__(256) void mlpqkv_kernel(
    const unsigned short* __restrict__ A, const unsigned short* __restrict__ W3c,
    const unsigned short* __restrict__ AWt, const float* __restrict__ a_bias,
    const float* __restrict__ skipv, const unsigned short* __restrict__ hres,
    const unsigned short* __restrict__ qkvw1, const float* __restrict__ fbias1,
    const unsigned char* __restrict__ mask,
    unsigned short* __restrict__ h1, unsigned short* __restrict__ qkv, int M)
{
    __shared__ unsigned short Bs[128 * 40];
    __shared__ unsigned short msgS[64 * 136];
    const int t = threadIdx.x;
    const int wave = t >> 6, lane = t & 63;
    const int quad = lane >> 4, l16 = lane & 15;
    const int row0 = blockIdx.x * 64;
    const int wcl = wave * 32;               // this wave's 32-col block; head == wave
    const int sr = t >> 1, scc = (t & 1) * 16;   // Bs staging: 128 rows x 32 shorts
    const int sr4 = t >> 2, sc4 = (t & 3) * 32;  // msgS staging: 64 rows, 4 thr/row x 32 shorts
    const int grow = row0 + sr4;
    const bool rvalid = grow < M;

    // ---- stage 1: block-diagonal, it == relation r, K=32 (head == wave) ----
    f32x4 acc[4][2];
    #pragma unroll
    for (int i = 0; i < 4; ++i)
        #pragma unroll
        for (int j = 0; j < 2; ++j)
            acc[i][j] = (f32x4){0.f, 0.f, 0.f, 0.f};

    uint4 av[4];
    #pragma unroll
    for (int j = 0; j < 4; ++j) av[j] = make_uint4(0, 0, 0, 0);
    if (rvalid) {
        const uint4* ap = (const uint4*)(A + (size_t)grow * 512 + sc4);
        #pragma unroll
        for (int j = 0; j < 4; ++j) av[j] = ap[j];
    }
    uint4 bw0, bw1;
    {
        const uint4* bp = (const uint4*)(W3c + sr * 32 + scc);
        bw0 = bp[0]; bw1 = bp[1];
    }
    for (int it = 0; it < 4; ++it) {
        __syncthreads();
        #pragma unroll
        for (int j = 0; j < 4; ++j)
            *(uint4*)(msgS + sr4 * 136 + sc4 + j * 8) = av[j];
        *(uint4*)(Bs + sr * 40 + scc)     = bw0;
        *(uint4*)(Bs + sr * 40 + scc + 8) = bw1;
        __syncthreads();
        if (it + 1 < 4) {
            if (rvalid) {
                const uint4* ap = (const uint4*)(A + (size_t)grow * 512 + (it + 1) * 128 + sc4);
                #pragma unroll
                for (int j = 0; j < 4; ++j) av[j] = ap[j];
            }
            const uint4* bp = (const uint4*)(W3c + (it + 1) * 4096 + sr * 32 + scc);
            bw0 = bp[0]; bw1 = bp[1];
        }
        bf16x8 af[4], bfr[2];
        #pragma unroll
        for (int f = 0; f < 4; ++f)
            af[f] = *(const bf16x8*)(msgS + (f * 16 + l16) * 136 + wave * 32 + quad * 8);
        #pragma unroll
        for (int f = 0; f < 2; ++f)
            bfr[f] = *(const bf16x8*)(Bs + (wcl + f * 16 + l16) * 40 + quad * 8);
        #pragma unroll
        for (int fr = 0; fr < 4; ++fr)
            #pragma unroll
            for (int fc = 0; fc < 2; ++fc)
                acc[fr][fc] = __builtin_amdgcn_mfma_f32_16x16x32_bf16(
                    af[fr], bfr[fc], acc[fr][fc], 0, 0, 0);
    }
    __syncthreads();      // all stage-1 msgS reads complete before gelu overwrite

    // gelu -> msgS
    #pragma unroll
    for (int fr = 0; fr < 4; ++fr)
        #pragma unroll
        for (int reg = 0; reg < 4; ++reg) {
            int rl = fr * 16 + quad * 4 + reg;
            #pragma unroll
            for (int fc = 0; fc < 2; ++fc) {
                int col = wcl + fc * 16 + l16;
                float v = acc[fr][fc][reg];
                float gl = 0.5f * v * (1.f + erff(v * 0.70710678118654752f));
                msgS[rl * 136 + col] = f2bf(gl);
            }
        }

    // stage 2: K = 128 from msgS vs AWt
    f32x4 acc2[4][2];
    #pragma unroll
    for (int i = 0; i < 4; ++i)
        #pragma unroll
        for (int j = 0; j < 2; ++j)
            acc2[i][j] = (f32x4){0.f, 0.f, 0.f, 0.f};
    uint4 pv0, pv1;
    {
        const uint4* bp = (const uint4*)(AWt + (size_t)sr * 128 + scc);
        pv0 = bp[0]; pv1 = bp[1];
    }
    for (int it = 0; it < 4; ++it) {
        __syncthreads();
        *(uint4*)(Bs + sr * 40 + scc)     = pv0;
        *(uint4*)(Bs + sr * 40 + scc + 8) = pv1;
        __syncthreads();
        if (it + 1 < 4) {
            const uint4* bp = (const uint4*)(AWt + (size_t)sr * 128 + (it + 1) * 32 + scc);
            pv0 = bp[0]; pv1 = bp[1];
        } else {       // prefetch stage-3 (ch=4, it=0)
            const uint4* bp = (const uint4*)(qkvw1 + (size_t)(4 * 128 + sr) * 128 + scc);
            pv0 = bp[0]; pv1 = bp[1];
        }
        bf16x8 af[4], bfr[2];
        #pragma unroll
        for (int f = 0; f < 4; ++f)
            af[f] = *(const bf16x8*)(msgS + (f * 16 + l16) * 136 + it * 32 + quad * 8);
        #pragma unroll
        for (int f = 0; f < 2; ++f)
            bfr[f] = *(const bf16x8*)(Bs + (wcl + f * 16 + l16) * 40 + quad * 8);
        #pragma unroll
        for (int fr = 0; fr < 4; ++fr)
            #pragma unroll
            for (int fc = 0; fc < 2; ++fc)
                acc2[fr][fc] = __builtin_amdgcn_mfma_f32_16x16x32_bf16(
                    af[fr], bfr[fc], acc2[fr][fc], 0, 0, 0);
    }

    const float gate = 1.f / (1.f + __expf(-skipv[0]));
    __syncthreads();                            // all stage-2 msgS reads complete
    #pragma unroll
    for (int fr = 0; fr < 4; ++fr)
        #pragma unroll
        for (int reg = 0; reg < 4; ++reg) {
            int rl = fr * 16 + quad * 4 + reg;
            int row = row0 + rl;
            const bool rv = row < M;
            const bool mw = rv && mask[row];    // h1 only ever read at idx rows
            #pragma unroll
            for (int fc = 0; fc < 2; ++fc) {
                int col = wcl + fc * 16 + l16;
                float val = acc2[fr][fc][reg] + a_bias[col];
                float nv = val;
                if (rv) {
                    unsigned int hu = hres[(size_t)row * 128 + col];
                    nv = gate * val + (1.f - gate) * bf2f(hu);
                    if (mw) h1[(size_t)row * 128 + col] = f2bf(nv);
                }
                msgS[rl * 136 + col] = f2bf(nv);   // h1 tile for stage 3
            }
        }

    // stage 3: qkv1 KV ONLY = h1 @ qkvw1^T cols 512..767 (K = 128 from msgS)
    for (int ch = 4; ch < 6; ++ch) {
        f32x4 acc3[4][2];
        #pragma unroll
        for (int i = 0; i < 4; ++i)
            #pragma unroll
            for (int j = 0; j < 2; ++j)
                acc3[i][j] = (f32x4){0.f, 0.f, 0.f, 0.f};
        for (int it = 0; it < 4; ++it) {
            __syncthreads();
            *(uint4*)(Bs + sr * 40 + scc)     = pv0;
            *(uint4*)(Bs + sr * 40 + scc + 8) = pv1;
            __syncthreads();
            int nit = it + 1, nch = ch;
            if (nit == 4) { nit = 0; ++nch; }
            if (nch < 6) {
                const uint4* bp = (const uint4*)(qkvw1 + (size_t)(nch * 128 + sr) * 128 + nit * 32 + scc);
                pv0 = bp[0]; pv1 = bp[1];
            }
            bf16x8 af[4], bfr[2];
            #pragma unroll
            for (int f = 0; f < 4; ++f)
                af[f] = *(const bf16x8*)(msgS + (f * 16 + l16) * 136 + it * 32 + quad * 8);
            #pragma unroll
            for (int f = 0; f < 2; ++f)
                bfr[f] = *(const bf16x8*)(Bs + (wcl + f * 16 + l16) * 40 + quad * 8);
            #pragma unroll
            for (int fr = 0; fr < 4; ++fr)
                #pragma unroll
                for (int fc = 0; fc < 2; ++fc)
                    acc3[fr][fc] = __builtin_amdgcn_mfma_f32_16x16x32_bf16(
                        af[fr], bfr[fc], acc3[fr][fc], 0, 0, 0);
        }
        float b2[2];
        #pragma unroll
        for (int fc = 0; fc < 2; ++fc)
            b2[fc] = fbias1[ch * 128 + wcl + fc * 16 + l16];
        #pragma unroll
        for (int fr = 0; fr < 4; ++fr)
            #pragma unroll
            for (int reg = 0; reg < 4; ++reg) {
                int row = row0 + fr * 16 + quad * 4 + reg;
                if (row >= M) continue;
                #pragma unroll
                for (int fc = 0; fc < 2; ++fc) {
                    int col = ch * 128 + wcl + fc * 16 + l16;
                    qkv[(size_t)row * 768 + col] = f2bf(acc3[fr][fc][reg] + b2[fc]);
                }
            }
    }
}

// ============ compact layer-1 q, CHUNK-SPLIT: gridDim.y=4, one col-chunk per block ============
__global__ __launch_bounds__(256) void q1_kernel(
    const unsigned short* __restrict__ h1, const int* __restrict__ idxp,
    const unsigned short* __restrict__ qkvw1, const float* __restrict__ fbias1,
    unsigned short* __restrict__ q1, int M)
{
    __shared__ unsigned short hS[128 * 136];
    __shared__ unsigned short Bs[128 * 40];
    const int t = threadIdx.x;
    const int row0 = blockIdx.x * 128;
    const int ch = blockIdx.y;
    #pragma unroll
    for (int u = 0; u < 8; ++u) {
        int li = t + u * 256;                 // uint4 index; 16 per row
        int row = li >> 4, c = li & 15;
        uint4 pk = make_uint4(0, 0, 0, 0);
        if (row0 + row < M) {
            int node = idxp[row0 + row];
            pk = ((const uint4*)(h1 + (size_t)node * 128))[c];
        }
        *(uint4*)(hS + row * 136 + c * 8) = pk;
    }
    __syncthreads();

    const int wave = t >> 6, lane = t & 63;
    const int quad = lane >> 4, l16 = lane & 15;
    const int wr = (wave & 1) * 64, wcl = (wave >> 1) * 64;
    const int sr = t >> 1, scc = (t & 1) * 16;
    uint4 pv0, pv1;
    {
        const uint4* bp = (const uint4*)(qkvw1 + (size_t)(ch * 128 + sr) * 128 + scc);
        pv0 = bp[0]; pv1 = bp[1];
    }
    f32x4 acc[4][4];
    #pragma unroll
    for (int i = 0; i < 4; ++i)
        #pragma unroll
        for (int j = 0; j < 4; ++j)
            acc[i][j] = (f32x4){0.f, 0.f, 0.f, 0.f};
    for (int it = 0; it < 4; ++it) {
        __syncthreads();
        *(uint4*)(Bs + sr * 40 + scc)     = pv0;
        *(uint4*)(Bs + sr * 40 + scc + 8) = pv1;
        __syncthreads();
        if (it + 1 < 4) {
            const uint4* bp = (const uint4*)(qkvw1 + (size_t)(ch * 128 + sr) * 128 + (it + 1) * 32 + scc);
            pv0 = bp[0]; pv1 = bp[1];
        }
        bf16x8 af[4], bfr[4];
        #pragma unroll
        for (int f = 0; f < 4; ++f) {
            af[f]  = *(const bf16x8*)(hS + (wr + f * 16 + l16) * 136 + it * 32 + quad * 8);
            bfr[f] = *(const bf16x8*)(Bs + (wcl + f * 16 + l16) * 40 + quad * 8);
        }
        #pragma unroll
        for (int fr = 0; fr < 4; ++fr)
            #pragma unroll
            for (int fc = 0; fc < 4; ++fc)
                acc[fr][fc] = __builtin_amdgcn_mfma_f32_16x16x32_bf16(
                    af[fr], bfr[fc], acc[fr][fc], 0, 0, 0);
    }
    float b4[4];
    #pragma unroll
    for (int fc = 0; fc < 4; ++fc)
        b4[fc] = fbias1[ch * 128 + wcl + fc * 16 + l16];
    #pragma unroll
    for (int fr = 0; fr < 4; ++fr)
        #pragma unroll
        for (int reg = 0; reg < 4; ++reg) {
            int row = row0 + wr + fr * 16 + quad * 4 + reg;
            if (row >= M) continue;
            #pragma unroll
            for (int fc = 0; fc < 4; ++fc) {
                int col = ch * 128 + wcl + fc * 16 + l16;
                q1[(size_t)row * 512 + col] = f2bf(acc[fr][fc][reg] + b4[fc]);
            }
        }
}

// ============ layer-1 MLP: 64-ROW TILES (same layout as mlpqkv, no stage 3) ============
__global__ __launch_bounds__(256) void mlp1_kernel(
    const unsigned short* __restrict__ A, const unsigned short* __restrict__ W3c,
    const unsigned short* __restrict__ AWt, const float* __restrict__ a_bias,
    const float* __restrict__ skipv, const unsigned short* __restrict__ hres,
    const int* __restrict__ rowmap, float* __restrict__ out, int M)
{
    __shared__ unsigned short Bs[128 * 40];
    __shared__ unsigned short msgS[64 * 136];
    const int t = threadIdx.x;
    const int wave = t >> 6, lane = t & 63;
    const int quad = lane >> 4, l16 = lane & 15;
    const int row0 = blockIdx.x * 64;
    const int wcl = wave * 32;
    const int sr = t >> 1, scc = (t & 1) * 16;
    const int sr4 = t >> 2, sc4 = (t & 3) * 32;
    const int grow = row0 + sr4;
    const bool rvalid = grow < M;

    f32x4 acc[4][2];
    #pragma unroll
    for (int i = 0; i < 4; ++i)
        #pragma unroll
        for (int j = 0; j < 2; ++j)
            acc[i][j] = (f32x4){0.f, 0.f, 0.f, 0.f};

    uint4 av[4];
    #pragma unroll
    for (int j = 0; j < 4; ++j) av[j] = make_uint4(0, 0, 0, 0);
    if (rvalid) {
        const uint4* ap = (const uint4*)(A + (size_t)grow * 512 + sc4);
        #pragma unroll
        for (int j = 0; j < 4; ++j) av[j] = ap[j];
    }
    uint4 bw0, bw1;
    {
        const uint4* bp = (const uint4*)(W3c + sr * 32 + scc);
        bw0 = bp[0]; bw1 = bp[1];
    }
    for (int it = 0; it < 4; ++it) {
        __syncthreads();
        #pragma unroll
        for (int j = 0; j < 4; ++j)
            *(uint4*)(msgS + sr4 * 136 + sc4 + j * 8) = av[j];
        *(uint4*)(Bs + sr * 40 + scc)     = bw0;
        *(uint4*)(Bs + sr * 40 + scc + 8) = bw1;
        __syncthreads();
        if (it + 1 < 4) {
            if (rvalid) {
                const uint4* ap = (const uint4*)(A + (size_t)grow * 512 + (it + 1) * 128 + sc4);
                #pragma unroll
                for (int j = 0; j < 4; ++j) av[j] = ap[j];
            }
            const uint4* bp = (const uint4*)(W3c + (it + 1) * 4096 + sr * 32 + scc);
            bw0 = bp[0]; bw1 = bp[1];
        }
        bf16x8 af[4], bfr[2];
        #pragma unroll
        for (int f = 0; f < 4; ++f)
            af[f] = *(const bf16x8*)(msgS + (f * 16 + l16) * 136 + wave * 32 + quad * 8);
        #pragma unroll
        for (int f = 0; f < 2; ++f)
            bfr[f] = *(const bf16x8*)(Bs + (wcl + f * 16 + l16) * 40 + quad * 8);
        #pragma unroll
        for (int fr = 0; fr < 4; ++fr)
            #pragma unroll
            for (int fc = 0; fc < 2; ++fc)
                acc[fr][fc] = __builtin_amdgcn_mfma_f32_16x16x32_bf16(
                    af[fr], bfr[fc], acc[fr][fc], 0, 0, 0);
    }
    __syncthreads();      // stage-1 msgS reads complete before gelu overwrite

    #pragma unroll
    for (int fr = 0; fr < 4; ++fr)
        #pragma unroll
        for (int reg = 0; reg < 4; ++reg) {
            int rl = fr * 16 + quad * 4 + reg;
            #pragma unroll
            for (int fc = 0; fc < 2; ++fc) {
                int col = wcl + fc * 16 + l16;
                float v = acc[fr][fc][reg];
                float gl = 0.5f * v * (1.f + erff(v * 0.70710678118654752f));
                msgS[rl * 136 + col] = f2bf(gl);
            }
        }

    f32x4 acc2[4][2];
    #pragma unroll
    for (int i = 0; i < 4; ++i)
        #pragma unroll
        for (int j = 0; j < 2; ++j)
            acc2[i][j] = (f32x4){0.f, 0.f, 0.f, 0.f};
    uint4 pv0, pv1;
    {
        const uint4* bp = (const uint4*)(AWt + (size_t)sr * 128 + scc);
        pv0 = bp[0]; pv1 = bp[1];
    }
    for (int it = 0; it < 4; ++it) {
        __syncthreads();
        *(uint4*)(Bs + sr * 40 + scc)     = pv0;
        *(uint4*)(Bs + sr * 40 + scc + 8) = pv1;
        __syncthreads();
        if (it + 1 < 4) {
            const uint4* bp = (const uint4*)(AWt + (size_t)sr * 128 + (it + 1) * 32 + scc);
            pv0 = bp[0]; pv1 = bp[1];
        }
        bf16x8 af[4], bfr[2];
        #pragma unroll
        for (int f = 0; f < 4; ++f)
            af[f] = *(const bf16x8*)(msgS + (f * 16 + l16) * 136 + it * 32 + quad * 8);
        #pragma unroll
        for (int f = 0; f < 2; ++f)
            bfr[f] = *(const bf16x8*)(Bs + (wcl + f * 16 + l16) * 40 + quad * 8);
        #pragma unroll
        for (int fr = 0; fr < 4; ++fr)
            #pragma unroll
            for (int fc = 0; fc < 2; ++fc)
                acc2[fr][fc] = __builtin_amdgcn_mfma_f32_16x16x32_bf16(
                    af[fr], bfr[fc], acc2[fr][fc], 0, 0, 0);
    }

    const float gate = 1.f / (1.f + __expf(-skipv[0]));
    #pragma unroll
    for (int fr = 0; fr < 4; ++fr)
        #pragma unroll
        for (int reg = 0; reg < 4; ++reg) {
            int row = row0 + fr * 16 + quad * 4 + reg;
            if (row >= M) continue;
            int hrow = rowmap[row];
            #pragma unroll
            for (int fc = 0; fc < 2; ++fc) {
                int col = wcl + fc * 16 + l16;
                float val = acc2[fr][fc][reg] + a_bias[col];
                float nv = gate * val + (1.f - gate) * bf2f((unsigned int)hres[(size_t)hrow * 128 + col]);
                out[(size_t)row * 128 + col] = nv;
            }
        }
}

extern "C" void kernel_launch(void* const* d_in, const int* in_sizes, int n_in,
                              void* d_out, int out_size, void* d_ws, size_t ws_size,
                              hipStream_t stream)
{
    const float* x      = (const float*)d_in[0];
    const float* proj_w = (const float*)d_in[1];
    const float* proj_b = (const float*)d_in[2];
    const float* bn_g   = (const float*)d_in[3];
    const float* bn_b   = (const float*)d_in[4];
    const float* q_w    = (const float*)d_in[5];
    const float* q_b    = (const float*)d_in[6];
    const float* k_w    = (const float*)d_in[7];
    const float* k_b    = (const float*)d_in[8];
    const float* v_w    = (const float*)d_in[9];
    const float* v_b    = (const float*)d_in[10];
    const float* a_w    = (const float*)d_in[11];
    const float* a_b    = (const float*)d_in[12];
    const float* skip   = (const float*)d_in[13];
    const float* a_rel  = (const float*)d_in[14];
    const float* m_rel  = (const float*)d_in[15];
    const float* p_rel  = (const float*)d_in[16];
    const int* edge_index = (const int*)d_in[17];
    const int* edge_type  = (const int*)d_in[18];
    const int* idx        = (const int*)d_in[19];
    float* out = (float*)d_out;

    const int N = NN, E = EE;
    float* ws = (float*)d_ws;
    size_t o = 0;
    float* stats  = ws + o;  o += 256;
    float* fbias  = ws + o;  o += 2 * 768;
    int* cnt  = (int*)(ws + o); o += NT4;
    int* off4 = (int*)(ws + o); o += NT4 + 1;
    int* fill = (int*)(ws + o); o += NT4;
    int* bsum = (int*)(ws + o); o += 1024;
    int* pack = (int*)(ws + o); o += E;
    unsigned short* x_bf   = (unsigned short*)(ws + o); o += (size_t)N * 64;  // scratch; reused by q1
    unsigned short* h_bf   = (unsigned short*)(ws + o); o += (size_t)N * 64;
    unsigned short* hn_bf  = (unsigned short*)(ws + o); o += (size_t)N * 64;
    unsigned short* h1_bf  = (unsigned short*)(ws + o); o += (size_t)N * 64;
    unsigned short* qkv_bf = (unsigned short*)(ws + o); o += (size_t)N * 384;
    unsigned short* agg_bf = (unsigned short*)(ws + o); o += (size_t)N * 256;
    unsigned short* wt_pa  = (unsigned short*)(ws + o); o += 3 * 16384 / 2;
    unsigned short* qkvw   = (unsigned short*)(ws + o); o += 2 * 98304 / 2;
    unsigned short* msg_wt = (unsigned short*)(ws + o); o += 2 * 65536 / 2;   // uses first 2*16384 now

    // idx-membership mask (50000 bytes) reuses cnt[0:12500) — dead after scan_block.
    unsigned char* mask = (unsigned char*)cnt;
    // q1 compact buffer [MOUT][512] reuses x_bf region.
    unsigned short* q1 = x_bf;   // 10000*512 shorts = 5.12M <= N*128 shorts

    const int NB4 = (NT4 + 255) / 256;          // 782
    const int g = (N + 127) / 128;              // 391

    // 1) prep: weights (compact msg), zero cnt/stats
    prep_kernel<<<1088 + NB4, 256, 0, stream>>>(
        proj_w, a_w, q_w, q_b, a_rel, k_w, k_b, v_w, v_b, m_rel, p_rel,
        wt_pa, qkvw, fbias, msg_wt, cnt, stats);

    // 2-5) CSR build; scan_add zeroes mask region (cnt dead), scatter sets mask
    hist_kernel<<<(E + 255) / 256, 256, 0, stream>>>(edge_index, edge_type, cnt, E);
    scan_block_kernel<<<NB4, 256, 0, stream>>>(cnt, off4, bsum, NT4);
    scan_add_kernel<<<NB4, 256, 0, stream>>>(off4, bsum, fill, cnt, NT4, E);
    scatter_kernel<<<(E + 255) / 256, 256, 0, stream>>>(edge_index, edge_type, fill,
                                                        pack, idx, mask, MOUT, E);

    // 6) proj GEMM + BN stats (A = x f32, cast in-register)
    projstats_kernel<<<g, 256, 0, stream>>>(x, wt_pa, proj_b, h_bf, stats, N);

    // 7) BN apply + qkv0 — chunk-split: 3 blocks/row-tile, 2 chunks each
    {
        dim3 grid(g, 3);
        bnqkv_kernel<<<grid, 256, 0, stream>>>(h_bf, stats, bn_g, bn_b, qkvw, fbias,
                                               hn_bf, qkv_bf, N);
    }

    // 8) attention layer 0 (all nodes; pair-processing, 16B kv chunks)
    agg_fused_kernel<<<(N + 3) / 4, 256, 0, stream>>>(qkv_bf, qkv_bf, 768,
                                                      off4, pack, nullptr, agg_bf, N);

    // 9) MLP0 (64-row tiles, block-diag stage 1) + residual + qkv1 KV
    mlpqkv_kernel<<<(N + 63) / 64, 256, 0, stream>>>(agg_bf, msg_wt, wt_pa + 16384, a_b, skip,
                                                     hn_bf, qkvw + 98304, fbias + 768,
                                                     mask, h1_bf, qkv_bf, N);

    // 9.5) compact layer-1 q — chunk-split: 4 blocks/row-tile, 1 chunk each
    {
        dim3 gq((MOUT + 127) / 128, 4);
        q1_kernel<<<gq, 256, 0, stream>>>(h1_bf, idx, qkvw + 98304, fbias + 768, q1, MOUT);
    }

    // 10) attention layer 1 (idx rows; q from compact q1, kv gathered from qkv)
    agg_fused_kernel<<<(MOUT + 3) / 4, 256, 0, stream>>>(qkv_bf, q1, 512,
                                                         off4, pack, idx, agg_bf, MOUT);

    // 11) MLP1 (64-row tiles) + residual -> out
    mlp1_kernel<<<(MOUT + 63) / 64, 256, 0, stream>>>(agg_bf, msg_wt + 16384,
                                                      wt_pa + 2 * 16384, a_b + 128,
                                                      skip + 1, h1_bf, idx, out, MOUT);
}

// Round 13
// 390.988 us; speedup vs baseline: 1.1899x; 1.0301x over previous
//
#include <hip/hip_runtime.h>
#include <math.h>

#define NN 50000
#define EE 600000
#define MOUT 10000
#define DEGCAP 384
#define NT4 (NN * 4)

typedef short bf16x8 __attribute__((ext_vector_type(8)));
typedef float f32x4 __attribute__((ext_vector_type(4)));

__device__ __forceinline__ unsigned short f2bf(float x) {
    unsigned int u = __float_as_uint(x);
    u = (u + 0x7FFFu + ((u >> 16) & 1u)) >> 16;
    return (unsigned short)u;
}
__device__ __forceinline__ float bf2f(unsigned int b) {
    return __uint_as_float(b << 16);
}
__device__ __forceinline__ uint4 pack8bf(float4 a, float4 b) {
    uint4 r;
    r.x = (unsigned int)f2bf(a.x) | ((unsigned int)f2bf(a.y) << 16);
    r.y = (unsigned int)f2bf(a.z) | ((unsigned int)f2bf(a.w) << 16);
    r.z = (unsigned int)f2bf(b.x) | ((unsigned int)f2bf(b.y) << 16);
    r.w = (unsigned int)f2bf(b.z) | ((unsigned int)f2bf(b.w) << 16);
    return r;
}

// ============ merged weight prep + FUSED edge histogram (cnt/stats pre-zeroed by memset) ============
// qkv weight rows 512..767 PERMUTED into 16B chunks (k[4t..4t+3], v[4t..4t+3]);
// qrel rows pre-scaled by p_rel/sqrt(32).
// msg weight stored COMPACT block-diagonal: msg_wt2[(l*4+r)*4096 + n*32 + d]
//   = m_rel[l][r][h=n>>5][d][e=n&31].
__global__ __launch_bounds__(256) void prep_kernel(
    const float* __restrict__ proj_w, const float* __restrict__ a_w,
    const float* __restrict__ q_w, const float* __restrict__ q_b,
    const float* __restrict__ a_rel,
    const float* __restrict__ k_w, const float* __restrict__ k_b,
    const float* __restrict__ v_w, const float* __restrict__ v_b,
    const float* __restrict__ m_rel, const float* __restrict__ p_rel,
    const int* __restrict__ ei, const int* __restrict__ et,
    unsigned short* __restrict__ wt_pa, unsigned short* __restrict__ qkvw,
    float* __restrict__ fbias, unsigned short* __restrict__ msg_wt,
    int* __restrict__ cnt, int E)
{
    const int b = blockIdx.x, t = threadIdx.x;
    if (b < 192) {                       // proj^T, a_w0^T, a_w1^T
        int wi = b >> 6;
        int flat = (b & 63) * 256 + t;
        int n = flat >> 7, c = flat & 127;
        const float* src = (wi == 0) ? proj_w : (wi == 1) ? a_w : a_w + 16384;
        wt_pa[(size_t)wi * 16384 + n * 128 + c] = f2bf(src[c * 128 + n]);
    } else if (b < 960) {                // fused qkv weight [768][128] per layer
        int q = b - 192;
        int l = q >= 384 ? 1 : 0;
        int flat = (q - l * 384) * 256 + t;
        int nrow = flat >> 7, c = flat & 127;
        unsigned short* wt = qkvw + (size_t)l * 98304;
        float* fb = fbias + l * 768;
        if (nrow < 512) {
            int r = nrow >> 7, hh = (nrow >> 5) & 3, d = nrow & 31;
            float prl = p_rel[l * 16 + r * 4 + hh] * 0.17677669529663687f;
            const float* qwc = q_w + (size_t)l * 16384 + c * 128 + hh * 32;
            const float* ar  = a_rel + (size_t)(l * 4 + r) * 4096 + hh * 1024 + d * 32;
            float s = 0.f;
            #pragma unroll 8
            for (int e = 0; e < 32; ++e) s += qwc[e] * ar[e];
            wt[(size_t)nrow * 128 + c] = f2bf(s * prl);
            if (c == 0) {
                const float* qb = q_b + l * 128 + hh * 32;
                float bb = 0.f;
                #pragma unroll 8
                for (int e = 0; e < 32; ++e) bb += qb[e] * ar[e];
                fb[nrow] = bb * prl;
            }
        } else {                         // k/v 16B-chunk rows: t-th chunk = k[4t..4t+3], v[4t..4t+3]
            int j = nrow - 512;
            int tt = j >> 3, s = j & 7;
            int col = 4 * tt + (s & 3);
            const float* w  = (s < 4) ? k_w : v_w;
            const float* bb = (s < 4) ? k_b : v_b;
            wt[(size_t)nrow * 128 + c] = f2bf(w[(size_t)l * 16384 + c * 128 + col]);
            if (c == 0) fb[nrow] = bb[l * 128 + col];
        }
    } else if (b < 1088) {               // compact msg weight: 2 layers x 4 rel x [128 n][32 d]
        int q = b - 960;
        int l = q >= 64 ? 1 : 0;
        int flat = (q - l * 64) * 256 + t;     // 0 .. 16383
        int r = flat >> 12, rem = flat & 4095;
        int n = rem >> 5, d = rem & 31;
        float val = m_rel[(size_t)(l * 4 + r) * 4096 + (n >> 5) * 1024 + d * 32 + (n & 31)];
        msg_wt[(size_t)l * 16384 + r * 4096 + n * 32 + d] = f2bf(val);
    } else {                             // fused edge histogram
        int e = (b - 1088) * 256 + t;
        if (e < E) atomicAdd(&cnt[ei[E + e] * 4 + et[e]], 1);
    }
}

// ============ CSR scan ============
__global__ __launch_bounds__(256) void scan_block_kernel(const int* __restrict__ cnt,
    int* __restrict__ excl, int* __restrict__ bsum, int n)
{
    __shared__ int tmp[256];
    int i = blockIdx.x * 256 + threadIdx.x;
    int v = (i < n) ? cnt[i] : 0;
    tmp[threadIdx.x] = v;
    __syncthreads();
    for (int ofs = 1; ofs < 256; ofs <<= 1) {
        int t = (threadIdx.x >= ofs) ? tmp[threadIdx.x - ofs] : 0;
        __syncthreads();
        tmp[threadIdx.x] += t;
        __syncthreads();
    }
    if (i < n) excl[i] = tmp[threadIdx.x] - v;
    if (threadIdx.x == 255) bsum[blockIdx.x] = tmp[255];
}

// per-block prefix over bsum; ALSO zeroes the idx-mask region (reuses dead cnt[0:12500))
__global__ __launch_bounds__(256) void scan_add_kernel(int* __restrict__ excl,
    const int* __restrict__ bsum, int* __restrict__ fill,
    int* __restrict__ maskz, int n, int total)
{
    __shared__ int red[256];
    const int b = blockIdx.x;
    int partial = 0;
    for (int j = threadIdx.x; j < b; j += 256) partial += bsum[j];
    red[threadIdx.x] = partial;
    __syncthreads();
    for (int ofs = 128; ofs > 0; ofs >>= 1) {
        if (threadIdx.x < ofs) red[threadIdx.x] += red[threadIdx.x + ofs];
        __syncthreads();
    }
    int prefix = red[0];
    int i = b * 256 + threadIdx.x;
    if (i < n) {
        int o = excl[i] + prefix;
        excl[i] = o;
        fill[i] = o;
    }
    if (i < 12500) maskz[i] = 0;         // cnt region is dead after scan_block
    if (b == 0 && threadIdx.x == 0) excl[n] = total;
}

// ============ proj GEMM (64-ROW TILES) + BN-stats epilogue + FUSED scatter ============
// Blocks [0, psB): GEMM, 4 waves x (64 rows x 32 cols), A staged once (f32 cast in-reg).
// Blocks [psB, ...): CSR scatter + idx-mask set.
__global__ __launch_bounds__(256) void projstats_kernel(
    const float* __restrict__ X, const unsigned short* __restrict__ Wt,
    const float* __restrict__ bias, unsigned short* __restrict__ Cb,
    float* __restrict__ stats, int M,
    const int* __restrict__ ei, const int* __restrict__ et,
    int* __restrict__ fill, int* __restrict__ pack,
    const int* __restrict__ idxp, unsigned char* __restrict__ mask,
    int Mo, int E, int psB)
{
    __shared__ unsigned short As[64 * 136];
    __shared__ unsigned short Bs[128 * 40];
    const int t = threadIdx.x;
    if (blockIdx.x >= psB) {             // ---- scatter path ----
        int e = (blockIdx.x - psB) * 256 + t;
        if (e < E) {
            int seg = ei[E + e] * 4 + et[e];
            int p = atomicAdd(&fill[seg], 1);
            pack[p] = ei[e];
            if (e < Mo) mask[idxp[e]] = 1;
        }
        return;
    }
    const int wave = t >> 6, lane = t & 63;
    const int quad = lane >> 4, l16 = lane & 15;
    const int row0 = blockIdx.x * 64;
    const int wcl = wave * 32;
    const int sr = t >> 1, scc = (t & 1) * 16;     // Bs staging
    const int sr4 = t >> 2, sc4 = (t & 3) * 32;    // As staging: 4 thr/row x 32 shorts
    const int grow = row0 + sr4;
    const bool rvalid = grow < M;

    f32x4 acc[4][2];
    #pragma unroll
    for (int i = 0; i < 4; ++i)
        #pragma unroll
        for (int j = 0; j < 2; ++j)
            acc[i][j] = (f32x4){0.f, 0.f, 0.f, 0.f};

    uint4 av[4];
    #pragma unroll
    for (int j = 0; j < 4; ++j) av[j] = make_uint4(0, 0, 0, 0);
    if (rvalid) {
        const float4* ap = (const float4*)(X + (size_t)grow * 128 + sc4);
        #pragma unroll
        for (int j = 0; j < 4; ++j) av[j] = pack8bf(ap[2 * j], ap[2 * j + 1]);
    }
    uint4 pv0, pv1;
    {
        const uint4* bp = (const uint4*)(Wt + (size_t)sr * 128 + scc);
        pv0 = bp[0]; pv1 = bp[1];
    }
    for (int it = 0; it < 4; ++it) {
        __syncthreads();
        if (it == 0) {
            #pragma unroll
            for (int j = 0; j < 4; ++j)
                *(uint4*)(As + sr4 * 136 + sc4 + j * 8) = av[j];
        }
        *(uint4*)(Bs + sr * 40 + scc)     = pv0;
        *(uint4*)(Bs + sr * 40 + scc + 8) = pv1;
        __syncthreads();
        if (it + 1 < 4) {
            const uint4* bp = (const uint4*)(Wt + (size_t)sr * 128 + (it + 1) * 32 + scc);
            pv0 = bp[0]; pv1 = bp[1];
        }
        bf16x8 af[4], bfr[2];
        #pragma unroll
        for (int f = 0; f < 4; ++f)
            af[f] = *(const bf16x8*)(As + (f * 16 + l16) * 136 + it * 32 + quad * 8);
        #pragma unroll
        for (int f = 0; f < 2; ++f)
            bfr[f] = *(const bf16x8*)(Bs + (wcl + f * 16 + l16) * 40 + quad * 8);
        #pragma unroll
        for (int fr = 0; fr < 4; ++fr)
            #pragma unroll
            for (int fc = 0; fc < 2; ++fc)
                acc[fr][fc] = __builtin_amdgcn_mfma_f32_16x16x32_bf16(
                    af[fr], bfr[fc], acc[fr][fc], 0, 0, 0);
    }

    #pragma unroll
    for (int fc = 0; fc < 2; ++fc) {
        const int col = wcl + fc * 16 + l16;
        const float bv = bias[col];
        float s = 0.f, s2 = 0.f;
        #pragma unroll
        for (int fr = 0; fr < 4; ++fr)
            #pragma unroll
            for (int reg = 0; reg < 4; ++reg) {
                int row = row0 + fr * 16 + quad * 4 + reg;
                float val = acc[fr][fc][reg] + bv;
                if (row < M) {
                    Cb[(size_t)row * 128 + col] = f2bf(val);
                    s += val; s2 += val * val;
                }
            }
        s  += __shfl_xor(s, 16);  s  += __shfl_xor(s, 32);
        s2 += __shfl_xor(s2, 16); s2 += __shfl_xor(s2, 32);
        if (quad == 0) {
            atomicAdd(&stats[col], s);
            atomicAdd(&stats[128 + col], s2);
        }
    }
}

// ============ BN-apply + qkv0 GEMM, CHUNK-SPLIT: gridDim.y=3, 2 col-chunks per block ============
__global__ __launch_bounds__(256) void bnqkv_kernel(
    const unsigned short* __restrict__ hb, const float* __restrict__ stats,
    const float* __restrict__ gamma, const float* __restrict__ beta,
    const unsigned short* __restrict__ qkvw, const float* __restrict__ fbias,
    unsigned short* __restrict__ hn, unsigned short* __restrict__ qkv, int M)
{
    __shared__ unsigned short hS[128 * 136];
    __shared__ unsigned short Bs[128 * 40];
    __shared__ float mulS[128], addS[128];
    const int t = threadIdx.x;
    const int row0 = blockIdx.x * 128;
    const int ch0 = blockIdx.y * 2;
    if (t < 128) {
        float invN = 1.f / 50000.f;
        float mu = stats[t] * invN;
        float var = stats[128 + t] * invN - mu * mu;
        float ml = rsqrtf(var + 1e-5f) * gamma[t];
        mulS[t] = ml;
        addS[t] = beta[t] - mu * ml;
    }
    __syncthreads();
    #pragma unroll
    for (int u = 0; u < 8; ++u) {
        int li = t + u * 256;                 // uint4 index; 16 per row
        int row = li >> 4, c0 = (li & 15) * 8;
        uint4 pk = make_uint4(0, 0, 0, 0);
        if (row0 + row < M)
            pk = ((const uint4*)(hb + (size_t)(row0 + row) * 128))[li & 15];
        unsigned int w[4] = {pk.x, pk.y, pk.z, pk.w};
        uint4 o;
        unsigned int ov[4];
        #pragma unroll
        for (int g = 0; g < 4; ++g) {
            int c = c0 + g * 2;
            float a0 = bf2f(w[g] & 0xFFFFu) * mulS[c]     + addS[c];
            float a1 = bf2f(w[g] >> 16)     * mulS[c + 1] + addS[c + 1];
            ov[g] = (unsigned int)f2bf(a0) | ((unsigned int)f2bf(a1) << 16);
        }
        o.x = ov[0]; o.y = ov[1]; o.z = ov[2]; o.w = ov[3];
        *(uint4*)(hS + row * 136 + c0) = o;
        if (blockIdx.y == 0 && row0 + row < M)
            ((uint4*)(hn + (size_t)(row0 + row) * 128))[li & 15] = o;
    }
    __syncthreads();

    const int wave = t >> 6, lane = t & 63;
    const int quad = lane >> 4, l16 = lane & 15;
    const int wr = (wave & 1) * 64, wcl = (wave >> 1) * 64;
    const int sr = t >> 1, scc = (t & 1) * 16;

    // weight prefetch registers for (ch=ch0, it=0)
    uint4 pv0, pv1;
    {
        const uint4* bp = (const uint4*)(qkvw + (size_t)(ch0 * 128 + sr) * 128 + scc);
        pv0 = bp[0]; pv1 = bp[1];
    }
    for (int ch = ch0; ch < ch0 + 2; ++ch) {
        f32x4 acc[4][4];
        #pragma unroll
        for (int i = 0; i < 4; ++i)
            #pragma unroll
            for (int j = 0; j < 4; ++j)
                acc[i][j] = (f32x4){0.f, 0.f, 0.f, 0.f};
        for (int it = 0; it < 4; ++it) {
            __syncthreads();
            *(uint4*)(Bs + sr * 40 + scc)     = pv0;
            *(uint4*)(Bs + sr * 40 + scc + 8) = pv1;
            __syncthreads();
            int nit = it + 1, nch = ch;
            if (nit == 4) { nit = 0; ++nch; }
            if (nch < ch0 + 2) {
                const uint4* bp = (const uint4*)(qkvw + (size_t)(nch * 128 + sr) * 128 + nit * 32 + scc);
                pv0 = bp[0]; pv1 = bp[1];
            }
            bf16x8 af[4], bfr[4];
            #pragma unroll
            for (int f = 0; f < 4; ++f) {
                af[f]  = *(const bf16x8*)(hS + (wr + f * 16 + l16) * 136 + it * 32 + quad * 8);
                bfr[f] = *(const bf16x8*)(Bs + (wcl + f * 16 + l16) * 40 + quad * 8);
            }
            #pragma unroll
            for (int fr = 0; fr < 4; ++fr)
                #pragma unroll
                for (int fc = 0; fc < 4; ++fc)
                    acc[fr][fc] = __builtin_amdgcn_mfma_f32_16x16x32_bf16(
                        af[fr], bfr[fc], acc[fr][fc], 0, 0, 0);
        }
        float b4[4];
        #pragma unroll
        for (int fc = 0; fc < 4; ++fc)
            b4[fc] = fbias[ch * 128 + wcl + fc * 16 + l16];
        #pragma unroll
        for (int fr = 0; fr < 4; ++fr)
            #pragma unroll
            for (int reg = 0; reg < 4; ++reg) {
                int row = row0 + wr + fr * 16 + quad * 4 + reg;
                if (row >= M) continue;
                #pragma unroll
                for (int fc = 0; fc < 4; ++fc) {
                    int col = ch * 128 + wcl + fc * 16 + l16;
                    qkv[(size_t)row * 768 + col] = f2bf(acc[fr][fc][reg] + b4[fc]);
                }
            }
    }
}

// ============ fused attention: per-node wave, PAIR processing (2 edges across wave halves) ====
__global__ __launch_bounds__(256) void agg_fused_kernel(
    const unsigned short* __restrict__ qkv,
    const unsigned short* __restrict__ qbuf, int qpitch,
    const int* __restrict__ off4, const int* __restrict__ pack,
    const int* __restrict__ rowmap, unsigned short* __restrict__ aggb, int count)
{
    __shared__ int spack[4][DEGCAP];
    const int wv = threadIdx.x >> 6;
    const int lane = threadIdx.x & 63;
    const int l32 = lane & 31;
    const int hi = lane >> 5;
    const int unit = blockIdx.x * 4 + wv;
    if (unit >= count) return;                 // no __syncthreads in this kernel
    const int node = rowmap ? __builtin_amdgcn_readfirstlane(rowmap[unit]) : unit;

    // q dims [4*l32 .. 4*l32+3] per run (both halves need the same dims)
    const uint2* qrow = (const uint2*)(qbuf + (size_t)unit * qpitch);
    uint2 quv[4];
    #pragma unroll
    for (int r = 0; r < 4; ++r) quv[r] = qrow[r * 32 + l32];

    int off_r[5];
    #pragma unroll
    for (int i = 0; i < 5; ++i)
        off_r[i] = __builtin_amdgcn_readfirstlane(off4[node * 4 + i]);
    const int beg = off_r[0];
    const int deg = off_r[4] - beg;
    const bool cached = deg <= DEGCAP;

    if (cached) {
        for (int i = lane; i < deg; i += 64) spack[wv][i] = pack[beg + i];
        asm volatile("s_waitcnt vmcnt(0) lgkmcnt(0)" ::: "memory");
    }

    uint2 outw[4];
    #pragma unroll
    for (int r = 0; r < 4; ++r) {
        float q0 = bf2f(quv[r].x & 0xFFFFu), q1 = bf2f(quv[r].x >> 16);
        float q2 = bf2f(quv[r].y & 0xFFFFu), q3 = bf2f(quv[r].y >> 16);
        float den = 0.f, a0 = 0.f, a1 = 0.f, a2 = 0.f, a3 = 0.f;

        if (cached) {
            const int rb = off_r[r] - beg, re = off_r[r + 1] - beg;
            for (int i = rb; i < re; i += 4) {
                int i0 = i + hi;      if (i0 >= re) i0 = re - 1;
                int i1 = i + 2 + hi;  if (i1 >= re) i1 = re - 1;
                int s0 = spack[wv][i0], s1 = spack[wv][i1];
                uint4 kv0 = *(const uint4*)(qkv + (size_t)s0 * 768 + 512 + l32 * 8);
                uint4 kv1 = *(const uint4*)(qkv + (size_t)s1 * 768 + 512 + l32 * 8);
                {
                    float p = q0 * bf2f(kv0.x & 0xFFFFu) + q1 * bf2f(kv0.x >> 16)
                            + q2 * bf2f(kv0.y & 0xFFFFu) + q3 * bf2f(kv0.y >> 16);
                    p += __shfl_xor(p, 1); p += __shfl_xor(p, 2); p += __shfl_xor(p, 4);
                    float e = __expf(fminf(fmaxf(p, -80.f), 80.f));
                    if (i + hi >= re) e = 0.f;
                    den += e;
                    a0 += e * bf2f(kv0.z & 0xFFFFu); a1 += e * bf2f(kv0.z >> 16);
                    a2 += e * bf2f(kv0.w & 0xFFFFu); a3 += e * bf2f(kv0.w >> 16);
                }
                {
                    float p = q0 * bf2f(kv1.x & 0xFFFFu) + q1 * bf2f(kv1.x >> 16)
                            + q2 * bf2f(kv1.y & 0xFFFFu) + q3 * bf2f(kv1.y >> 16);
                    p += __shfl_xor(p, 1); p += __shfl_xor(p, 2); p += __shfl_xor(p, 4);
                    float e = __expf(fminf(fmaxf(p, -80.f), 80.f));
                    if (i + 2 + hi >= re) e = 0.f;
                    den += e;
                    a0 += e * bf2f(kv1.z & 0xFFFFu); a1 += e * bf2f(kv1.z >> 16);
                    a2 += e * bf2f(kv1.w & 0xFFFFu); a3 += e * bf2f(kv1.w >> 16);
                }
            }
        } else {   // giant-degree fallback: pair walk straight from pack
            const int pe_end = off_r[r + 1];
            for (int pp = off_r[r]; pp < pe_end; pp += 2) {
                int pe = pp + hi; if (pe >= pe_end) pe = pe_end - 1;
                int src = pack[pe];
                uint4 kv = *(const uint4*)(qkv + (size_t)src * 768 + 512 + l32 * 8);
                float p = q0 * bf2f(kv.x & 0xFFFFu) + q1 * bf2f(kv.x >> 16)
                        + q2 * bf2f(kv.y & 0xFFFFu) + q3 * bf2f(kv.y >> 16);
                p += __shfl_xor(p, 1); p += __shfl_xor(p, 2); p += __shfl_xor(p, 4);
                float e = __expf(fminf(fmaxf(p, -80.f), 80.f));
                if (pp + hi >= pe_end) e = 0.f;
                den += e;
                a0 += e * bf2f(kv.z & 0xFFFFu); a1 += e * bf2f(kv.z >> 16);
                a2 += e * bf2f(kv.w & 0xFFFFu); a3 += e * bf2f(kv.w >> 16);
            }
        }
        // merge the two halves (lane l and l+32 hold the same dims, different edges)
        den += __shfl_xor(den, 32);
        a0  += __shfl_xor(a0, 32);
        a1  += __shfl_xor(a1, 32);
        a2  += __shfl_xor(a2, 32);
        a3  += __shfl_xor(a3, 32);
        float inv = den > 0.f ? 1.f / den : 0.f;
        outw[r].x = (unsigned int)f2bf(a0 * inv) | ((unsigned int)f2bf(a1 * inv) << 16);
        outw[r].y = (unsigned int)f2bf(a2 * inv) | ((unsigned int)f2bf(a3 * inv) << 16);
    }
    if (hi == 0) {
        uint2* op = (uint2*)(aggb + (size_t)unit * 512);
        #pragma unroll
        for (int r = 0; r < 4; ++r) op[r * 32 + l32] = outw[r];
    }
}

// ============ layer-0 MLP + qkv1-kv: 64-ROW TILES, 4 waves x (64 rows x 32 cols) ============
// h1 = gate*(gelu(agg@W3)@AW + b) + (1-g)*hn; qkv1 kv cols for ALL nodes;
// h1 stored only at idx rows (mask). Stage 1 block-diagonal: each wave's 32-col
// block is exactly one head -> single A-fragment group.
__global__ __launch_bounds__(256) void mlpqkv_kernel(
    const unsigned short* __restrict__ A, const unsigned short* __restrict__ W3c,
    const unsigned short* __restrict__ AWt, const float* __restrict__ a_bias,
    const float* __restrict__ skipv, const unsigned short* __restrict__ hres,
    const unsigned short* __restrict__ qkvw1, const float* __restrict__ fbias1,
    const unsigned char* __restrict__ mask,
    unsigned short* __restrict__ h1, unsigned short* __restrict__ qkv, int M)
{
    __shared__ unsigned short Bs[128 * 40];
    __shared__ unsigned short msgS[64 * 136];
    const int t = threadIdx.x;
    const int wave = t >> 6, lane = t & 63;
    const int quad = lane >> 4, l16 = lane & 15;
    const int row0 = blockIdx.x * 64;
    const int wcl = wave * 32;               // this wave's 32-col block; head == wave
    const int sr = t >> 1, scc = (t & 1) * 16;   // Bs staging: 128 rows x 32 shorts
    const int sr4 = t >> 2, sc4 = (t & 3) * 32;  // msgS staging: 64 rows, 4 thr/row x 32 shorts
    const int grow = row0 + sr4;
    const bool rvalid = grow < M;

    // ---- stage 1: block-diagonal, it == relation r, K=32 (head == wave) ----
    f32x4 acc[4][2];
    #pragma unroll
    for (int i = 0; i < 4; ++i)
        #pragma unroll
        for (int j = 0; j < 2; ++j)
            acc[i][j] = (f32x4){0.f, 0.f, 0.f, 0.f};

    uint4 av[4];
    #pragma unroll
    for (int j = 0; j < 4; ++j) av[j] = make_uint4(0, 0, 0, 0);
    if (rvalid) {
        const uint4* ap = (const uint4*)(A + (size_t)grow * 512 + sc4);
        #pragma unroll
        for (int j = 0; j < 4; ++j) av[j] = ap[j];
    }
    uint4 bw0, bw1;
    {
        const uint4* bp = (const uint4*)(W3c + sr * 32 + scc);
        bw0 = bp[0]; bw1 = bp[1];
    }
    for (int it = 0; it < 4; ++it) {
        __syncthreads();
        #pragma unroll
        for (int j = 0; j < 4; ++j)
            *(uint4*)(msgS + sr4 * 136 + sc4 + j * 8) = av[j];
        *(uint4*)(Bs + sr * 40 + scc)     = bw0;
        *(uint4*)(Bs + sr * 40 + scc + 8) = bw1;
        __syncthreads();
        if (it + 1 < 4) {
            if (rvalid) {
                const uint4* ap = (const uint4*)(A + (size_t)grow * 512 + (it + 1) * 128 + sc4);
                #pragma unroll
                for (int j = 0; j < 4; ++j) av[j] = ap[j];
            }
            const uint4* bp = (const uint4*)(W3c + (it + 1) * 4096 + sr * 32 + scc);
            bw0 = bp[0]; bw1 = bp[1];
        }
        bf16x8 af[4], bfr[2];
        #pragma unroll
        for (int f = 0; f < 4; ++f)
            af[f] = *(const bf16x8*)(msgS + (f * 16 + l16) * 136 + wave * 32 + quad * 8);
        #pragma unroll
        for (int f = 0; f < 2; ++f)
            bfr[f] = *(const bf16x8*)(Bs + (wcl + f * 16 + l16) * 40 + quad * 8);
        #pragma unroll
        for (int fr = 0; fr < 4; ++fr)
            #pragma unroll
            for (int fc = 0; fc < 2; ++fc)
                acc[fr][fc] = __builtin_amdgcn_mfma_f32_16x16x32_bf16(
                    af[fr], bfr[fc], acc[fr][fc], 0, 0, 0);
    }
    __syncthreads();      // all stage-1 msgS reads complete before gelu overwrite

    // gelu -> msgS
    #pragma unroll
    for (int fr = 0; fr < 4; ++fr)
        #pragma unroll
        for (int reg = 0; reg < 4; ++reg) {
            int rl = fr * 16 + quad * 4 + reg;
            #pragma unroll
            for (int fc = 0; fc < 2; ++fc) {
                int col = wcl + fc * 16 + l16;
                float v = acc[fr][fc][reg];
                float gl = 0.5f * v * (1.f + erff(v * 0.70710678118654752f));
                msgS[rl * 136 + col] = f2bf(gl);
            }
        }

    // stage 2: K = 128 from msgS vs AWt
    f32x4 acc2[4][2];
    #pragma unroll
    for (int i = 0; i < 4; ++i)
        #pragma unroll
        for (int j = 0; j < 2; ++j)
            acc2[i][j] = (f32x4){0.f, 0.f, 0.f, 0.f};
    uint4 pv0, pv1;
    {
        const uint4* bp = (const uint4*)(AWt + (size_t)sr * 128 + scc);
        pv0 = bp[0]; pv1 = bp[1];
    }
    for (int it = 0; it < 4; ++it) {
        __syncthreads();
        *(uint4*)(Bs + sr * 40 + scc)     = pv0;
        *(uint4*)(Bs + sr * 40 + scc + 8) = pv1;
        __syncthreads();
        if (it + 1 < 4) {
            const uint4* bp = (const uint4*)(AWt + (size_t)sr * 128 + (it + 1) * 32 + scc);
            pv0 = bp[0]; pv1 = bp[1];
        } else {       // prefetch stage-3 (ch=4, it=0)
            const uint4* bp = (const uint4*)(qkvw1 + (size_t)(4 * 128 + sr) * 128 + scc);
            pv0 = bp[0]; pv1 = bp[1];
        }
        bf16x8 af[4], bfr[2];
        #pragma unroll
        for (int f = 0; f < 4; ++f)
            af[f] = *(const bf16x8*)(msgS + (f * 16 + l16) * 136 + it * 32 + quad * 8);
        #pragma unroll
        for (int f = 0; f < 2; ++f)
            bfr[f] = *(const bf16x8*)(Bs + (wcl + f * 16 + l16) * 40 + quad * 8);
        #pragma unroll
        for (int fr = 0; fr < 4; ++fr)
            #pragma unroll
            for (int fc = 0; fc < 2; ++fc)
                acc2[fr][fc] = __builtin_amdgcn_mfma_f32_16x16x32_bf16(
                    af[fr], bfr[fc], acc2[fr][fc], 0, 0, 0);
    }

    const float gate = 1.f / (1.f + __expf(-skipv[0]));
    __syncthreads();                            // all stage-2 msgS reads complete
    #pragma unroll
    for (int fr = 0; fr < 4; ++fr)
        #pragma unroll
        for (int reg = 0; reg < 4; ++reg) {
            int rl = fr * 16 + quad * 4 + reg;
            int row = row0 + rl;
            const bool rv = row < M;
            const bool mw = rv && mask[row];    // h1 only ever read at idx rows
            #pragma unroll
            for (int fc = 0; fc < 2; ++fc) {
                int col = wcl + fc * 16 + l16;
                float val = acc2[fr][fc][reg] + a_bias[col];
                float nv = val;
                if (rv) {
                    unsigned int hu = hres[(size_t)row * 128 + col];
                    nv = gate * val + (1.f - gate) * bf2f(hu);
                    if (mw) h1[(size_t)row * 128 + col] = f2bf(nv);
                }
                msgS[rl * 136 + col] = f2bf(nv);   // h1 tile for stage 3
            }
        }

    // stage 3: qkv1 KV ONLY = h1 @ qkvw1^T cols 512..767 (K = 128 from msgS)
    for (int ch = 4; ch < 6; ++ch) {
        f32x4 acc3[4][2];
        #pragma unroll
        for (int i = 0; i < 4; ++i)
            #pragma unroll
            for (int j = 0; j < 2; ++j)
                acc3[i][j] = (f32x4){0.f, 0.f, 0.f, 0.f};
        for (int it = 0; it < 4; ++it) {
            __syncthreads();
            *(uint4*)(Bs + sr * 40 + scc)     = pv0;
            *(uint4*)(Bs + sr * 40 + scc + 8) = pv1;
            __syncthreads();
            int nit = it + 1, nch = ch;
            if (nit == 4) { nit = 0; ++nch; }
            if (nch < 6) {
                const uint4* bp = (const uint4*)(qkvw1 + (size_t)(nch * 128 + sr) * 128 + nit * 32 + scc);
                pv0 = bp[0]; pv1 = bp[1];
            }
            bf16x8 af[4], bfr[2];
            #pragma unroll
            for (int f = 0; f < 4; ++f)
                af[f] = *(const bf16x8*)(msgS + (f * 16 + l16) * 136 + it * 32 + quad * 8);
            #pragma unroll
            for (int f = 0; f < 2; ++f)
                bfr[f] = *(const bf16x8*)(Bs + (wcl + f * 16 + l16) * 40 + quad * 8);
            #pragma unroll
            for (int fr = 0; fr < 4; ++fr)
                #pragma unroll
                for (int fc = 0; fc < 2; ++fc)
                    acc3[fr][fc] = __builtin_amdgcn_mfma_f32_16x16x32_bf16(
                        af[fr], bfr[fc], acc3[fr][fc], 0, 0, 0);
        }
        float b2[2];
        #pragma unroll
        for (int fc = 0; fc < 2; ++fc)
            b2[fc] = fbias1[ch * 128 + wcl + fc * 16 + l16];
        #pragma unroll
        for (int fr = 0; fr < 4; ++fr)
            #pragma unroll
            for (int reg = 0; reg < 4; ++reg) {
                int row = row0 + fr * 16 + quad * 4 + reg;
                if (row >= M) continue;
                #pragma unroll
                for (int fc = 0; fc < 2; ++fc) {
                    int col = ch * 128 + wcl + fc * 16 + l16;
                    qkv[(size_t)row * 768 + col] = f2bf(acc3[fr][fc][reg] + b2[fc]);
                }
            }
    }
}

// ============ compact layer-1 q, CHUNK-SPLIT: gridDim.y=4, one col-chunk per block ============
__global__ __launch_bounds__(256) void q1_kernel(
    const unsigned short* __restrict__ h1, const int* __restrict__ idxp,
    const unsigned short* __restrict__ qkvw1, const float* __restrict__ fbias1,
    unsigned short* __restrict__ q1, int M)
{
    __shared__ unsigned short hS[128 * 136];
    __shared__ unsigned short Bs[128 * 40];
    const int t = threadIdx.x;
    const int row0 = blockIdx.x * 128;
    const int ch = blockIdx.y;
    #pragma unroll
    for (int u = 0; u < 8; ++u) {
        int li = t + u * 256;                 // uint4 index; 16 per row
        int row = li >> 4, c = li & 15;
        uint4 pk = make_uint4(0, 0, 0, 0);
        if (row0 + row < M) {
            int node = idxp[row0 + row];
            pk = ((const uint4*)(h1 + (size_t)node * 128))[c];
        }
        *(uint4*)(hS + row * 136 + c * 8) = pk;
    }
    __syncthreads();

    const int wave = t >> 6, lane = t & 63;
    const int quad = lane >> 4, l16 = lane & 15;
    const int wr = (wave & 1) * 64, wcl = (wave >> 1) * 64;
    const int sr = t >> 1, scc = (t & 1) * 16;
    uint4 pv0, pv1;
    {
        const uint4* bp = (const uint4*)(qkvw1 + (size_t)(ch * 128 + sr) * 128 + scc);
        pv0 = bp[0]; pv1 = bp[1];
    }
    f32x4 acc[4][4];
    #pragma unroll
    for (int i = 0; i < 4; ++i)
        #pragma unroll
        for (int j = 0; j < 4; ++j)
            acc[i][j] = (f32x4){0.f, 0.f, 0.f, 0.f};
    for (int it = 0; it < 4; ++it) {
        __syncthreads();
        *(uint4*)(Bs + sr * 40 + scc)     = pv0;
        *(uint4*)(Bs + sr * 40 + scc + 8) = pv1;
        __syncthreads();
        if (it + 1 < 4) {
            const uint4* bp = (const uint4*)(qkvw1 + (size_t)(ch * 128 + sr) * 128 + (it + 1) * 32 + scc);
            pv0 = bp[0]; pv1 = bp[1];
        }
        bf16x8 af[4], bfr[4];
        #pragma unroll
        for (int f = 0; f < 4; ++f) {
            af[f]  = *(const bf16x8*)(hS + (wr + f * 16 + l16) * 136 + it * 32 + quad * 8);
            bfr[f] = *(const bf16x8*)(Bs + (wcl + f * 16 + l16) * 40 + quad * 8);
        }
        #pragma unroll
        for (int fr = 0; fr < 4; ++fr)
            #pragma unroll
            for (int fc = 0; fc < 4; ++fc)
                acc[fr][fc] = __builtin_amdgcn_mfma_f32_16x16x32_bf16(
                    af[fr], bfr[fc], acc[fr][fc], 0, 0, 0);
    }
    float b4[4];
    #pragma unroll
    for (int fc = 0; fc < 4; ++fc)
        b4[fc] = fbias1[ch * 128 + wcl + fc * 16 + l16];
    #pragma unroll
    for (int fr = 0; fr < 4; ++fr)
        #pragma unroll
        for (int reg = 0; reg < 4; ++reg) {
            int row = row0 + wr + fr * 16 + quad * 4 + reg;
            if (row >= M) continue;
            #pragma unroll
            for (int fc = 0; fc < 4; ++fc) {
                int col = ch * 128 + wcl + fc * 16 + l16;
                q1[(size_t)row * 512 + col] = f2bf(acc[fr][fc][reg] + b4[fc]);
            }
        }
}

// ============ layer-1 MLP: 64-ROW TILES (same layout as mlpqkv, no stage 3) ============
__global__ __launch_bounds__(256) void mlp1_kernel(
    const unsigned short* __restrict__ A, const unsigned short* __restrict__ W3c,
    const unsigned short* __restrict__ AWt, const float* __restrict__ a_bias,
    const float* __restrict__ skipv, const unsigned short* __restrict__ hres,
    const int* __restrict__ rowmap, float* __restrict__ out, int M)
{
    __shared__ unsigned short Bs[128 * 40];
    __shared__ unsigned short msgS[64 * 136];
    const int t = threadIdx.x;
    const int wave = t >> 6, lane = t & 63;
    const int quad = lane >> 4, l16 = lane & 15;
    const int row0 = blockIdx.x * 64;
    const int wcl = wave * 32;
    const int sr = t >> 1, scc = (t & 1) * 16;
    const int sr4 = t >> 2, sc4 = (t & 3) * 32;
    const int grow = row0 + sr4;
    const bool rvalid = grow < M;

    f32x4 acc[4][2];
    #pragma unroll
    for (int i = 0; i < 4; ++i)
        #pragma unroll
        for (int j = 0; j < 2; ++j)
            acc[i][j] = (f32x4){0.f, 0.f, 0.f, 0.f};

    uint4 av[4];
    #pragma unroll
    for (int j = 0; j < 4; ++j) av[j] = make_uint4(0, 0, 0, 0);
    if (rvalid) {
        const uint4* ap = (const uint4*)(A + (size_t)grow * 512 + sc4);
        #pragma unroll
        for (int j = 0; j < 4; ++j) av[j] = ap[j];
    }
    uint4 bw0, bw1;
    {
        const uint4* bp = (const uint4*)(W3c + sr * 32 + scc);
        bw0 = bp[0]; bw1 = bp[1];
    }
    for (int it = 0; it < 4; ++it) {
        __syncthreads();
        #pragma unroll
        for (int j = 0; j < 4; ++j)
            *(uint4*)(msgS + sr4 * 136 + sc4 + j * 8) = av[j];
        *(uint4*)(Bs + sr * 40 + scc)     = bw0;
        *(uint4*)(Bs + sr * 40 + scc + 8) = bw1;
        __syncthreads();
        if (it + 1 < 4) {
            if (rvalid) {
                const uint4* ap = (const uint4*)(A + (size_t)grow * 512 + (it + 1) * 128 + sc4);
                #pragma unroll
                for (int j = 0; j < 4; ++j) av[j] = ap[j];
            }
            const uint4* bp = (const uint4*)(W3c + (it + 1) * 4096 + sr * 32 + scc);
            bw0 = bp[0]; bw1 = bp[1];
        }
        bf16x8 af[4], bfr[2];
        #pragma unroll
        for (int f = 0; f < 4; ++f)
            af[f] = *(const bf16x8*)(msgS + (f * 16 + l16) * 136 + wave * 32 + quad * 8);
        #pragma unroll
        for (int f = 0; f < 2; ++f)
            bfr[f] = *(const bf16x8*)(Bs + (wcl + f * 16 + l16) * 40 + quad * 8);
        #pragma unroll
        for (int fr = 0; fr < 4; ++fr)
            #pragma unroll
            for (int fc = 0; fc < 2; ++fc)
                acc[fr][fc] = __builtin_amdgcn_mfma_f32_16x16x32_bf16(
                    af[fr], bfr[fc], acc[fr][fc], 0, 0, 0);
    }
    __syncthreads();      // stage-1 msgS reads complete before gelu overwrite

    #pragma unroll
    for (int fr = 0; fr < 4; ++fr)
        #pragma unroll
        for (int reg = 0; reg < 4; ++reg) {
            int rl = fr * 16 + quad * 4 + reg;
            #pragma unroll
            for (int fc = 0; fc < 2; ++fc) {
                int col = wcl + fc * 16 + l16;
                float v = acc[fr][fc][reg];
                float gl = 0.5f * v * (1.f + erff(v * 0.70710678118654752f));
                msgS[rl * 136 + col] = f2bf(gl);
            }
        }

    f32x4 acc2[4][2];
    #pragma unroll
    for (int i = 0; i < 4; ++i)
        #pragma unroll
        for (int j = 0; j < 2; ++j)
            acc2[i][j] = (f32x4){0.f, 0.f, 0.f, 0.f};
    uint4 pv0, pv1;
    {
        const uint4* bp = (const uint4*)(AWt + (size_t)sr * 128 + scc);
        pv0 = bp[0]; pv1 = bp[1];
    }
    for (int it = 0; it < 4; ++it) {
        __syncthreads();
        *(uint4*)(Bs + sr * 40 + scc)     = pv0;
        *(uint4*)(Bs + sr * 40 + scc + 8) = pv1;
        __syncthreads();
        if (it + 1 < 4) {
            const uint4* bp = (const uint4*)(AWt + (size_t)sr * 128 + (it + 1) * 32 + scc);
            pv0 = bp[0]; pv1 = bp[1];
        }
        bf16x8 af[4], bfr[2];
        #pragma unroll
        for (int f = 0; f < 4; ++f)
            af[f] = *(const bf16x8*)(msgS + (f * 16 + l16) * 136 + it * 32 + quad * 8);
        #pragma unroll
        for (int f = 0; f < 2; ++f)
            bfr[f] = *(const bf16x8*)(Bs + (wcl + f * 16 + l16) * 40 + quad * 8);
        #pragma unroll
        for (int fr = 0; fr < 4; ++fr)
            #pragma unroll
            for (int fc = 0; fc < 2; ++fc)
                acc2[fr][fc] = __builtin_amdgcn_mfma_f32_16x16x32_bf16(
                    af[fr], bfr[fc], acc2[fr][fc], 0, 0, 0);
    }

    const float gate = 1.f / (1.f + __expf(-skipv[0]));
    #pragma unroll
    for (int fr = 0; fr < 4; ++fr)
        #pragma unroll
        for (int reg = 0; reg < 4; ++reg) {
            int row = row0 + fr * 16 + quad * 4 + reg;
            if (row >= M) continue;
            int hrow = rowmap[row];
            #pragma unroll
            for (int fc = 0; fc < 2; ++fc) {
                int col = wcl + fc * 16 + l16;
                float val = acc2[fr][fc][reg] + a_bias[col];
                float nv = gate * val + (1.f - gate) * bf2f((unsigned int)hres[(size_t)hrow * 128 + col]);
                out[(size_t)row * 128 + col] = nv;
            }
        }
}

extern "C" void kernel_launch(void* const* d_in, const int* in_sizes, int n_in,
                              void* d_out, int out_size, void* d_ws, size_t ws_size,
                              hipStream_t stream)
{
    const float* x      = (const float*)d_in[0];
    const float* proj_w = (const float*)d_in[1];
    const float* proj_b = (const float*)d_in[2];
    const float* bn_g   = (const float*)d_in[3];
    const float* bn_b   = (const float*)d_in[4];
    const float* q_w    = (const float*)d_in[5];
    const float* q_b    = (const float*)d_in[6];
    const float* k_w    = (const float*)d_in[7];
    const float* k_b    = (const float*)d_in[8];
    const float* v_w    = (const float*)d_in[9];
    const float* v_b    = (const float*)d_in[10];
    const float* a_w    = (const float*)d_in[11];
    const float* a_b    = (const float*)d_in[12];
    const float* skip   = (const float*)d_in[13];
    const float* a_rel  = (const float*)d_in[14];
    const float* m_rel  = (const float*)d_in[15];
    const float* p_rel  = (const float*)d_in[16];
    const int* edge_index = (const int*)d_in[17];
    const int* edge_type  = (const int*)d_in[18];
    const int* idx        = (const int*)d_in[19];
    float* out = (float*)d_out;

    const int N = NN, E = EE;
    float* ws = (float*)d_ws;
    size_t o = 0;
    float* stats  = ws + o;  o += 256;
    float* fbias  = ws + o;  o += 2 * 768;
    int* cnt  = (int*)(ws + o); o += NT4;
    int* off4 = (int*)(ws + o); o += NT4 + 1;
    int* fill = (int*)(ws + o); o += NT4;
    int* bsum = (int*)(ws + o); o += 1024;
    int* pack = (int*)(ws + o); o += E;
    unsigned short* x_bf   = (unsigned short*)(ws + o); o += (size_t)N * 64;  // scratch; reused by q1
    unsigned short* h_bf   = (unsigned short*)(ws + o); o += (size_t)N * 64;
    unsigned short* hn_bf  = (unsigned short*)(ws + o); o += (size_t)N * 64;
    unsigned short* h1_bf  = (unsigned short*)(ws + o); o += (size_t)N * 64;
    unsigned short* qkv_bf = (unsigned short*)(ws + o); o += (size_t)N * 384;
    unsigned short* agg_bf = (unsigned short*)(ws + o); o += (size_t)N * 256;
    unsigned short* wt_pa  = (unsigned short*)(ws + o); o += 3 * 16384 / 2;
    unsigned short* qkvw   = (unsigned short*)(ws + o); o += 2 * 98304 / 2;
    unsigned short* msg_wt = (unsigned short*)(ws + o); o += 2 * 65536 / 2;   // uses first 2*16384 now

    // idx-membership mask (50000 bytes) reuses cnt[0:12500) — dead after scan_block.
    unsigned char* mask = (unsigned char*)cnt;
    // q1 compact buffer [MOUT][512] reuses x_bf region.
    unsigned short* q1 = x_bf;   // 10000*512 shorts = 5.12M <= N*128 shorts

    const int NB4 = (NT4 + 255) / 256;          // 782
    const int EB  = (E + 255) / 256;            // 2344
    const int PSB = (N + 63) / 64;              // 782 GEMM blocks in projstats

    // 0) zero cnt + stats (stream-ordered; graph-capture safe)
    hipMemsetAsync(stats, 0, 256 * sizeof(float), stream);
    hipMemsetAsync(cnt, 0, (size_t)NT4 * sizeof(int), stream);

    // 1) prep: weights (compact msg) + FUSED edge histogram
    prep_kernel<<<1088 + EB, 256, 0, stream>>>(
        proj_w, a_w, q_w, q_b, a_rel, k_w, k_b, v_w, v_b, m_rel, p_rel,
        edge_index, edge_type,
        wt_pa, qkvw, fbias, msg_wt, cnt, E);

    // 2-3) CSR scan; scan_add zeroes mask region (cnt dead after scan_block)
    scan_block_kernel<<<NB4, 256, 0, stream>>>(cnt, off4, bsum, NT4);
    scan_add_kernel<<<NB4, 256, 0, stream>>>(off4, bsum, fill, cnt, NT4, E);

    // 4) proj GEMM (64-row tiles) + BN stats + FUSED scatter (+ idx-mask set)
    projstats_kernel<<<PSB + EB, 256, 0, stream>>>(x, wt_pa, proj_b, h_bf, stats, N,
                                                   edge_index, edge_type, fill, pack,
                                                   idx, mask, MOUT, E, PSB);

    // 5) BN apply + qkv0 — chunk-split: 3 blocks/row-tile, 2 chunks each
    {
        dim3 grid((N + 127) / 128, 3);
        bnqkv_kernel<<<grid, 256, 0, stream>>>(h_bf, stats, bn_g, bn_b, qkvw, fbias,
                                               hn_bf, qkv_bf, N);
    }

    // 6) attention layer 0 (all nodes; pair-processing, 16B kv chunks)
    agg_fused_kernel<<<(N + 3) / 4, 256, 0, stream>>>(qkv_bf, qkv_bf, 768,
                                                      off4, pack, nullptr, agg_bf, N);

    // 7) MLP0 (64-row tiles, block-diag stage 1) + residual + qkv1 KV
    mlpqkv_kernel<<<(N + 63) / 64, 256, 0, stream>>>(agg_bf, msg_wt, wt_pa + 16384, a_b, skip,
                                                     hn_bf, qkvw + 98304, fbias + 768,
                                                     mask, h1_bf, qkv_bf, N);

    // 8) compact layer-1 q — chunk-split: 4 blocks/row-tile, 1 chunk each
    {
        dim3 gq((MOUT + 127) / 128, 4);
        q1_kernel<<<gq, 256, 0, stream>>>(h1_bf, idx, qkvw + 98304, fbias + 768, q1, MOUT);
    }

    // 9) attention layer 1 (idx rows; q from compact q1, kv gathered from qkv)
    agg_fused_kernel<<<(MOUT + 3) / 4, 256, 0, stream>>>(qkv_bf, q1, 512,
                                                         off4, pack, idx, agg_bf, MOUT);

    // 10) MLP1 (64-row tiles) + residual -> out
    mlp1_kernel<<<(MOUT + 63) / 64, 256, 0, stream>>>(agg_bf, msg_wt + 16384,
                                                      wt_pa + 2 * 16384, a_b + 128,
                                                      skip + 1, h1_bf, idx, out, MOUT);
}